// Round 1
// baseline (4663.001 us; speedup 1.0000x reference)
//
#include <hip/hip_runtime.h>
#include <math.h>

#define C_DIM 512
#define WH    16384
#define CAP   17408      // 16384 + 8*128 worst-case padding
#define SEG_ALIGN 128
#define NCHUNK 64
#define CHUNK  256
#define NMAT 16
#define MSZ  (C_DIM*C_DIM)
#define ALPHA_C 0.8f
#define EPS_C   1e-6f
#define NIT 10
#define PIT 20

// ---------- label bookkeeping (deterministic counting sort) ----------

__global__ __launch_bounds__(256) void k_chunk_hist(const int* __restrict__ labels,
                                                    int* __restrict__ chunkCnt){
    __shared__ int h[8];
    int t = threadIdx.x;
    if (t < 8) h[t] = 0;
    __syncthreads();
    int l = labels[blockIdx.x*CHUNK + t];
    atomicAdd(&h[l], 1);
    __syncthreads();
    if (t < 8) chunkCnt[blockIdx.x*8 + t] = h[t];
}

__global__ void k_scan(const int* __restrict__ chunkCnt, int* __restrict__ cnt,
                       int* __restrict__ offPad, int* __restrict__ base){
    if (threadIdx.x != 0) return;
    int c[8];
    for (int k=0;k<8;k++) c[k]=0;
    for (int ch=0; ch<NCHUNK; ch++)
        for (int k=0;k<8;k++) c[k] += chunkCnt[ch*8+k];
    int off = 0;
    for (int k=0;k<8;k++){
        cnt[k] = c[k];
        offPad[k] = off;
        off += ((c[k] + SEG_ALIGN - 1)/SEG_ALIGN)*SEG_ALIGN;
    }
    offPad[8] = off;
    for (int k=0;k<8;k++){
        int run = offPad[k];
        for (int ch=0; ch<NCHUNK; ch++){
            base[ch*8+k] = run;
            run += chunkCnt[ch*8+k];
        }
    }
}

__global__ void k_place(const int* __restrict__ labels, const int* __restrict__ base,
                        int* __restrict__ perm){
    int t = threadIdx.x;
    if (t >= 8) return;
    int ch = blockIdx.x;
    int pos = base[ch*8+t];
    int s = ch*CHUNK;
    for (int i=0;i<CHUNK;i++){
        if (labels[s+i] == t) perm[pos++] = s+i;
    }
}

__global__ __launch_bounds__(256) void k_gather(const float* __restrict__ src,
        const int* __restrict__ perm, const int* __restrict__ offPad,
        const int* __restrict__ cnt, float* __restrict__ dst){
    __shared__ int so[9], sc[8];
    int t = threadIdx.x;
    if (t < 9) so[t] = offPad[t];
    if (t < 8) sc[t] = cnt[t];
    __syncthreads();
    int c = blockIdx.y;
    int i = blockIdx.x*256 + t;
    float v = 0.0f;
    if (i < so[8]){
        int k = 0;
        while (k < 7 && i >= so[k+1]) k++;
        int rel = i - so[k];
        if (rel < sc[k]) v = src[(size_t)c*WH + perm[i]];
    }
    dst[(size_t)c*CAP + i] = v;
}

// ---------- per-cluster sums / means ----------

template<bool DIV_N>
__global__ __launch_bounds__(256) void k_segsum(const float* __restrict__ X,
        const int* __restrict__ offPad, const int* __restrict__ cnt,
        float* __restrict__ out){
    int k = blockIdx.x;
    int c = blockIdx.y*32 + (threadIdx.x >> 3);
    int s = threadIdx.x & 7;
    int off = offPad[k], n = cnt[k];
    const float* row = X + (size_t)c*CAP + off;
    float acc = 0.0f;
    for (int j=s; j<n; j+=8) acc += row[j];
    for (int d=1; d<8; d<<=1) acc += __shfl_xor(acc, d);
    if (s == 0) out[k*C_DIM + c] = DIV_N ? acc/(float)n : acc;
}

__global__ __launch_bounds__(256) void k_style_mean(const float* __restrict__ scores,
        const int* __restrict__ cntS, const float* __restrict__ ssum,
        float* __restrict__ total, float* __restrict__ smean){
    int t = threadIdx.x;
    __shared__ float tot[8];
    if (t < 8){
        float s = 0.0f;
        for (int j=0;j<8;j++) s += scores[t*8+j]*(float)cntS[j];
        tot[t] = s; total[t] = s;
    }
    __syncthreads();
    for (int idx=t; idx<8*C_DIM; idx+=256){
        int k = idx / C_DIM, c = idx % C_DIM;
        float s = 0.0f;
        for (int j=0;j<8;j++) s += scores[k*8+j]*ssum[j*C_DIM+c];
        smean[idx] = s / tot[k];
    }
}

// ---------- segment SYRK: cov (content: centered, scaled, +eps; style: raw S2) ----------

template<bool CONTENT>
__global__ __launch_bounds__(256) void k_syrk(const float* __restrict__ X,
        const int* __restrict__ offPad, const int* __restrict__ cnt,
        const float* __restrict__ mean, float* __restrict__ out){
    __shared__ __align__(16) float AsI[16][132];
    __shared__ __align__(16) float AsJ[16][132];
    __shared__ float mI[128], mJ[128];
    int k = blockIdx.z;
    int i0 = blockIdx.y*128, j0 = blockIdx.x*128;
    int t = threadIdx.x;
    int tx = t & 15, ty = t >> 4;
    int off = offPad[k];
    int npad = offPad[k+1] - off;
    int n = cnt[k];
    if (CONTENT){
        if (t < 128) mI[t] = mean[k*C_DIM + i0 + t];
        else mJ[t-128] = mean[k*C_DIM + j0 + (t-128)];
    }
    __syncthreads();
    float acc[8][8] = {};
    const float* Xoff = X + off;
    for (int p=0; p<npad; p+=16){
        #pragma unroll
        for (int q=t; q<512; q+=256){
            int row = q>>2, kq = q&3;
            int pp = p + kq*4;
            float4 v = *(const float4*)&Xoff[(size_t)(i0+row)*CAP + pp];
            if (CONTENT){
                float m = mI[row];
                v.x = (pp+0 < n) ? (v.x - m) : 0.0f;
                v.y = (pp+1 < n) ? (v.y - m) : 0.0f;
                v.z = (pp+2 < n) ? (v.z - m) : 0.0f;
                v.w = (pp+3 < n) ? (v.w - m) : 0.0f;
            }
            AsI[kq*4+0][row]=v.x; AsI[kq*4+1][row]=v.y;
            AsI[kq*4+2][row]=v.z; AsI[kq*4+3][row]=v.w;
        }
        #pragma unroll
        for (int q=t; q<512; q+=256){
            int row = q>>2, kq = q&3;
            int pp = p + kq*4;
            float4 v = *(const float4*)&Xoff[(size_t)(j0+row)*CAP + pp];
            if (CONTENT){
                float m = mJ[row];
                v.x = (pp+0 < n) ? (v.x - m) : 0.0f;
                v.y = (pp+1 < n) ? (v.y - m) : 0.0f;
                v.z = (pp+2 < n) ? (v.z - m) : 0.0f;
                v.w = (pp+3 < n) ? (v.w - m) : 0.0f;
            }
            AsJ[kq*4+0][row]=v.x; AsJ[kq*4+1][row]=v.y;
            AsJ[kq*4+2][row]=v.z; AsJ[kq*4+3][row]=v.w;
        }
        __syncthreads();
        #pragma unroll
        for (int kk=0; kk<16; kk++){
            float a[8], b[8];
            *(float4*)&a[0] = *(const float4*)&AsI[kk][ty*8];
            *(float4*)&a[4] = *(const float4*)&AsI[kk][ty*8+4];
            *(float4*)&b[0] = *(const float4*)&AsJ[kk][tx*8];
            *(float4*)&b[4] = *(const float4*)&AsJ[kk][tx*8+4];
            #pragma unroll
            for (int ii=0; ii<8; ii++)
                #pragma unroll
                for (int jj=0; jj<8; jj++)
                    acc[ii][jj] = fmaf(a[ii], b[jj], acc[ii][jj]);
        }
        __syncthreads();
    }
    float scale = CONTENT ? 1.0f/((float)n - 1.0f) : 1.0f;
    float* O = out + (size_t)k*MSZ;
    for (int ii=0; ii<8; ii++){
        int gi = i0 + ty*8 + ii;
        for (int jj=0; jj<8; jj++){
            int gj = j0 + tx*8 + jj;
            float v = acc[ii][jj]*scale;
            if (CONTENT && gi == gj) v += EPS_C;
            O[(size_t)gi*C_DIM + gj] = v;
        }
    }
}

// ---------- style A assembly ----------

__global__ __launch_bounds__(256) void k_style_A(const float* __restrict__ S2,
        const float* __restrict__ scores, const float* __restrict__ total,
        const float* __restrict__ smean, float* __restrict__ Aout){
    int k = blockIdx.y;
    int e = blockIdx.x*256 + threadIdx.x;
    int i = e >> 9, j = e & 511;
    float s = 0.0f;
    #pragma unroll
    for (int jj=0;jj<8;jj++) s += scores[k*8+jj]*S2[(size_t)jj*MSZ + e];
    float tot = total[k];
    Aout[(size_t)k*MSZ + e] = (s - tot*smean[k*C_DIM+i]*smean[k*C_DIM+j]) / (tot - 1.0f);
}

// ---------- power iteration for lambda_max ----------

__global__ __launch_bounds__(256) void k_power(const float* __restrict__ A,
                                               float* __restrict__ tvals){
    __shared__ float vs[512];
    __shared__ float red[256];
    int b = blockIdx.x, t = threadIdx.x;
    const float* M = A + (size_t)b*MSZ;
    vs[t] = 1.0f; vs[t+256] = 1.0f;
    __syncthreads();
    float rho = 1.0f;
    for (int it=0; it<PIT; it++){
        const float* r0 = M + (size_t)t*C_DIM;
        const float* r1 = M + (size_t)(t+256)*C_DIM;
        float w0=0.f, w1=0.f;
        for (int d=0; d<C_DIM; d++){
            float vd = vs[d];
            w0 = fmaf(r0[d], vd, w0);
            w1 = fmaf(r1[d], vd, w1);
        }
        float lvw = vs[t]*w0 + vs[t+256]*w1;
        float lww = w0*w0 + w1*w1;
        red[t] = lww; __syncthreads();
        for (int s=128; s>0; s>>=1){ if (t<s) red[t]+=red[t+s]; __syncthreads(); }
        float nw = sqrtf(red[0]);
        __syncthreads();
        red[t] = lvw; __syncthreads();
        for (int s=128; s>0; s>>=1){ if (t<s) red[t]+=red[t+s]; __syncthreads(); }
        rho = red[0];
        __syncthreads();
        float inv = 1.0f/nw;
        vs[t] = w0*inv; vs[t+256] = w1*inv;
        __syncthreads();
    }
    if (t == 0) tvals[b] = 1.25f*fabsf(rho);
}

__global__ __launch_bounds__(256) void k_initYZ(float* __restrict__ Y,
        float* __restrict__ Z, const float* __restrict__ tvals){
    int idx = blockIdx.x*256 + threadIdx.x;   // over NMAT*MSZ = 2^22
    int b = idx >> 18;
    int e = idx & (MSZ-1);
    float inv = 1.0f / tvals[b];
    Y[(size_t)idx] *= inv;
    Z[(size_t)idx] = ((e>>9) == (e&511)) ? 1.0f : 0.0f;
}

// ---------- batched 512x512 matmul; MODE 0: A*B, 1: A*q(B), 2: q(A)*B, q(X)=1.5I-0.5X ----------

template<int MODE>
__global__ __launch_bounds__(256) void k_mm(const float* __restrict__ A,
        const float* __restrict__ B, float* __restrict__ Cm){
    __shared__ __align__(16) float As[16][132];
    __shared__ __align__(16) float Bs[16][132];
    int bz = blockIdx.z;
    const float* Ab = A + (size_t)bz*MSZ;
    const float* Bb = B + (size_t)bz*MSZ;
    float* Cb = Cm + (size_t)bz*MSZ;
    int i0 = blockIdx.y*128, j0 = blockIdx.x*128;
    int t = threadIdx.x, tx = t & 15, ty = t >> 4;
    float acc[8][8] = {};
    for (int k0=0; k0<512; k0+=16){
        #pragma unroll
        for (int q=t; q<512; q+=256){
            int row = q>>2, kq = q&3;
            int gr = i0 + row, gc = k0 + kq*4;
            float4 v = *(const float4*)&Ab[(size_t)gr*512 + gc];
            if (MODE == 2){
                v.x = ((gr==gc+0)?1.5f:0.0f) - 0.5f*v.x;
                v.y = ((gr==gc+1)?1.5f:0.0f) - 0.5f*v.y;
                v.z = ((gr==gc+2)?1.5f:0.0f) - 0.5f*v.z;
                v.w = ((gr==gc+3)?1.5f:0.0f) - 0.5f*v.w;
            }
            As[kq*4+0][row]=v.x; As[kq*4+1][row]=v.y;
            As[kq*4+2][row]=v.z; As[kq*4+3][row]=v.w;
        }
        #pragma unroll
        for (int q=t; q<512; q+=256){
            int kr = q>>5, nq = q&31;
            int gr = k0 + kr, gc = j0 + nq*4;
            float4 v = *(const float4*)&Bb[(size_t)gr*512 + gc];
            if (MODE == 1){
                v.x = ((gr==gc+0)?1.5f:0.0f) - 0.5f*v.x;
                v.y = ((gr==gc+1)?1.5f:0.0f) - 0.5f*v.y;
                v.z = ((gr==gc+2)?1.5f:0.0f) - 0.5f*v.z;
                v.w = ((gr==gc+3)?1.5f:0.0f) - 0.5f*v.w;
            }
            *(float4*)&Bs[kr][nq*4] = v;
        }
        __syncthreads();
        #pragma unroll
        for (int kk=0; kk<16; kk++){
            float a[8], b[8];
            *(float4*)&a[0] = *(const float4*)&As[kk][ty*8];
            *(float4*)&a[4] = *(const float4*)&As[kk][ty*8+4];
            *(float4*)&b[0] = *(const float4*)&Bs[kk][tx*8];
            *(float4*)&b[4] = *(const float4*)&Bs[kk][tx*8+4];
            #pragma unroll
            for (int ii=0; ii<8; ii++)
                #pragma unroll
                for (int jj=0; jj<8; jj++)
                    acc[ii][jj] = fmaf(a[ii], b[jj], acc[ii][jj]);
        }
        __syncthreads();
    }
    for (int ii=0; ii<8; ii++){
        float* dst = Cb + (size_t)(i0+ty*8+ii)*512 + j0 + tx*8;
        *(float4*)dst     = make_float4(acc[ii][0],acc[ii][1],acc[ii][2],acc[ii][3]);
        *(float4*)(dst+4) = make_float4(acc[ii][4],acc[ii][5],acc[ii][6],acc[ii][7]);
    }
}

// ---------- fold transforms ----------

__global__ __launch_bounds__(256) void k_buildM(const float* __restrict__ T,
        const float* __restrict__ tvals, float* __restrict__ M){
    int k = blockIdx.y;
    int e = blockIdx.x*256 + threadIdx.x;
    float scale = ALPHA_C * sqrtf(tvals[8+k]/tvals[k]);
    float v = scale * T[(size_t)k*MSZ + e];
    if ((e>>9) == (e&511)) v += (1.0f - ALPHA_C);
    M[(size_t)k*MSZ + e] = v;
}

__global__ __launch_bounds__(256) void k_buildV(const float* __restrict__ T,
        const float* __restrict__ tvals, const float* __restrict__ cmean,
        const float* __restrict__ smean, float* __restrict__ vvec){
    __shared__ float cm[512];
    int k = blockIdx.x, t = threadIdx.x;
    cm[t] = cmean[k*C_DIM + t];
    cm[t+256] = cmean[k*C_DIM + t + 256];
    __syncthreads();
    float scale = ALPHA_C * sqrtf(tvals[8+k]/tvals[k]);
    for (int c=t; c<C_DIM; c+=256){
        const float* row = T + (size_t)k*MSZ + (size_t)c*C_DIM;
        float s = 0.0f;
        for (int d=0; d<C_DIM; d++) s = fmaf(row[d], cm[d], s);
        vvec[k*C_DIM + c] = ALPHA_C*smean[k*C_DIM + c] - scale*s;
    }
}

// ---------- apply affine + scatter ----------

__global__ __launch_bounds__(256) void k_apply(const float* __restrict__ M,
        const float* __restrict__ Xc, const float* __restrict__ vvec,
        const int* __restrict__ offPad, const int* __restrict__ cnt,
        const int* __restrict__ perm, float* __restrict__ out){
    __shared__ __align__(16) float As[16][132];
    __shared__ __align__(16) float Bs[16][132];
    __shared__ int so[9], scn[8];
    int t = threadIdx.x;
    if (t < 9) so[t] = offPad[t];
    if (t < 8) scn[t] = cnt[t];
    __syncthreads();
    int j0 = blockIdx.x*128;
    if (j0 >= so[8]) return;
    int k = 0;
    while (k < 7 && j0 >= so[k+1]) k++;
    int i0 = blockIdx.y*128;
    const float* Mk = M + (size_t)k*MSZ;
    int tx = t & 15, ty = t >> 4;
    float acc[8][8] = {};
    for (int k0=0; k0<512; k0+=16){
        #pragma unroll
        for (int q=t; q<512; q+=256){
            int row = q>>2, kq = q&3;
            float4 v = *(const float4*)&Mk[(size_t)(i0+row)*512 + k0 + kq*4];
            As[kq*4+0][row]=v.x; As[kq*4+1][row]=v.y;
            As[kq*4+2][row]=v.z; As[kq*4+3][row]=v.w;
        }
        #pragma unroll
        for (int q=t; q<512; q+=256){
            int kr = q>>5, nq = q&31;
            float4 v = *(const float4*)&Xc[(size_t)(k0+kr)*CAP + j0 + nq*4];
            *(float4*)&Bs[kr][nq*4] = v;
        }
        __syncthreads();
        #pragma unroll
        for (int kk=0; kk<16; kk++){
            float a[8], b[8];
            *(float4*)&a[0] = *(const float4*)&As[kk][ty*8];
            *(float4*)&a[4] = *(const float4*)&As[kk][ty*8+4];
            *(float4*)&b[0] = *(const float4*)&Bs[kk][tx*8];
            *(float4*)&b[4] = *(const float4*)&Bs[kk][tx*8+4];
            #pragma unroll
            for (int ii=0; ii<8; ii++)
                #pragma unroll
                for (int jj=0; jj<8; jj++)
                    acc[ii][jj] = fmaf(a[ii], b[jj], acc[ii][jj]);
        }
        __syncthreads();
    }
    int rel0 = j0 - so[k];
    int n = scn[k];
    for (int ii=0; ii<8; ii++){
        int gi = i0 + ty*8 + ii;
        float vb = vvec[k*C_DIM + gi];
        for (int jj=0; jj<8; jj++){
            int rel = rel0 + tx*8 + jj;
            if (rel < n){
                int p = perm[j0 + tx*8 + jj];
                out[(size_t)gi*WH + p] = acc[ii][jj] + vb;
            }
        }
    }
}

// ---------- host ----------

extern "C" void kernel_launch(void* const* d_in, const int* in_sizes, int n_in,
                              void* d_out, int out_size, void* d_ws, size_t ws_size,
                              hipStream_t stream) {
    (void)in_sizes; (void)n_in;
    const float* cf     = (const float*)d_in[0];
    const float* sf     = (const float*)d_in[1];
    const float* scores = (const float*)d_in[2];
    const int*   cl     = (const int*)d_in[3];
    const int*   sl     = (const int*)d_in[4];
    float* out = (float*)d_out;
    float* ws  = (float*)d_ws;

    size_t o = 0;
    float* Xc = ws + o; o += (size_t)C_DIM*CAP;
    float* Xs = ws + o; o += (size_t)C_DIM*CAP;
    float* Y  = ws + o; o += (size_t)NMAT*MSZ;   // holds A, then Y iterate (in place)
    float* Z  = ws + o; o += (size_t)NMAT*MSZ;
    float* Y2 = ws + o; o += (size_t)NMAT*MSZ;   // aliased: S2 (pre-NS), M (post-NS)
    float* Z2 = ws + o; o += (size_t)NMAT*MSZ;
    float* P  = ws + o; o += (size_t)NMAT*MSZ;   // aliased: T (post-NS)
    float* cmean = ws + o; o += 8*C_DIM;
    float* ssum  = ws + o; o += 8*C_DIM;
    float* smean = ws + o; o += 8*C_DIM;
    float* vvec  = ws + o; o += 8*C_DIM;
    float* tvals = ws + o; o += 16;
    float* total = ws + o; o += 8;
    int* ip = (int*)(ws + o);
    int* permC = ip; ip += CAP;
    int* permS = ip; ip += CAP;
    int* cntC  = ip; ip += 8;
    int* cntS  = ip; ip += 8;
    int* offC  = ip; ip += 9;
    int* offS  = ip; ip += 9;
    int* chC   = ip; ip += NCHUNK*8;
    int* chS   = ip; ip += NCHUNK*8;
    int* baseC = ip; ip += NCHUNK*8;
    int* baseS = ip; ip += NCHUNK*8;
    size_t need_bytes = (size_t)((char*)ip - (char*)d_ws);
    if (ws_size < need_bytes){
        hipMemcpyAsync(d_out, (const void*)cf, (size_t)out_size*sizeof(float),
                       hipMemcpyDeviceToDevice, stream);
        return;
    }
    float* S2buf = Y2;
    float* Mbuf  = Y2;

    k_chunk_hist<<<NCHUNK,256,0,stream>>>(cl, chC);
    k_chunk_hist<<<NCHUNK,256,0,stream>>>(sl, chS);
    k_scan<<<1,64,0,stream>>>(chC, cntC, offC, baseC);
    k_scan<<<1,64,0,stream>>>(chS, cntS, offS, baseS);
    k_place<<<NCHUNK,64,0,stream>>>(cl, baseC, permC);
    k_place<<<NCHUNK,64,0,stream>>>(sl, baseS, permS);

    dim3 gg(CAP/256, C_DIM);
    k_gather<<<gg,256,0,stream>>>(cf, permC, offC, cntC, Xc);
    k_gather<<<gg,256,0,stream>>>(sf, permS, offS, cntS, Xs);

    k_segsum<true><<<dim3(8,16),256,0,stream>>>(Xc, offC, cntC, cmean);
    k_segsum<false><<<dim3(8,16),256,0,stream>>>(Xs, offS, cntS, ssum);
    k_style_mean<<<1,256,0,stream>>>(scores, cntS, ssum, total, smean);

    k_syrk<true><<<dim3(4,4,8),256,0,stream>>>(Xc, offC, cntC, cmean, Y);        // A[0..8)
    k_syrk<false><<<dim3(4,4,8),256,0,stream>>>(Xs, offS, cntS, nullptr, S2buf); // raw S2
    k_style_A<<<dim3(MSZ/256,8),256,0,stream>>>(S2buf, scores, total, smean, Y + (size_t)8*MSZ);

    k_power<<<NMAT,256,0,stream>>>(Y, tvals);
    k_initYZ<<<(NMAT*MSZ)/256,256,0,stream>>>(Y, Z, tvals);

    float *ya=Y, *za=Z, *yb=Y2, *zb=Z2;
    for (int it=0; it<NIT; it++){
        k_mm<0><<<dim3(4,4,NMAT),256,0,stream>>>(za, ya, P);   // P = Z*Y
        k_mm<1><<<dim3(4,4,NMAT),256,0,stream>>>(ya, P, yb);   // Y' = Y*q(P)
        k_mm<2><<<dim3(4,4,NMAT),256,0,stream>>>(P, za, zb);   // Z' = q(P)*Z
        float* tmp;
        tmp = ya; ya = yb; yb = tmp;
        tmp = za; za = zb; zb = tmp;
    }
    // NIT even -> final iterates in Y,Z. T[k] = Y_style[8+k] * Z_content[k]
    k_mm<0><<<dim3(4,4,8),256,0,stream>>>(ya + (size_t)8*MSZ, za, P);

    k_buildM<<<dim3(MSZ/256,8),256,0,stream>>>(P, tvals, Mbuf);
    k_buildV<<<8,256,0,stream>>>(P, tvals, cmean, smean, vvec);

    k_apply<<<dim3(CAP/128,4),256,0,stream>>>(Mbuf, Xc, vvec, offC, cntC, permC, out);
}

// Round 2
// 2112.975 us; speedup vs baseline: 2.2068x; 2.2068x over previous
//
#include <hip/hip_runtime.h>
#include <math.h>

#define C_DIM 512
#define WH    16384
#define CAP   17408      // 16384 + 8*128 worst-case padding
#define SEG_ALIGN 128
#define NCHUNK 64
#define CHUNK  256
#define NMAT 16
#define MSZ  (C_DIM*C_DIM)
#define ALPHA_C 0.8f
#define EPS_C   1e-6f
#define NIT 13

typedef __attribute__((ext_vector_type(8))) __bf16 bfrag;
typedef __attribute__((ext_vector_type(4))) float f32x4;

// ---------- label bookkeeping (deterministic counting sort) ----------

__global__ __launch_bounds__(256) void k_chunk_hist(const int* __restrict__ labels,
                                                    int* __restrict__ chunkCnt){
    __shared__ int h[8];
    int t = threadIdx.x;
    if (t < 8) h[t] = 0;
    __syncthreads();
    int l = labels[blockIdx.x*CHUNK + t];
    atomicAdd(&h[l], 1);
    __syncthreads();
    if (t < 8) chunkCnt[blockIdx.x*8 + t] = h[t];
}

__global__ void k_scan(const int* __restrict__ chunkCnt, int* __restrict__ cnt,
                       int* __restrict__ offPad, int* __restrict__ base){
    if (threadIdx.x != 0) return;
    int c[8];
    for (int k=0;k<8;k++) c[k]=0;
    for (int ch=0; ch<NCHUNK; ch++)
        for (int k=0;k<8;k++) c[k] += chunkCnt[ch*8+k];
    int off = 0;
    for (int k=0;k<8;k++){
        cnt[k] = c[k];
        offPad[k] = off;
        off += ((c[k] + SEG_ALIGN - 1)/SEG_ALIGN)*SEG_ALIGN;
    }
    offPad[8] = off;
    for (int k=0;k<8;k++){
        int run = offPad[k];
        for (int ch=0; ch<NCHUNK; ch++){
            base[ch*8+k] = run;
            run += chunkCnt[ch*8+k];
        }
    }
}

__global__ void k_place(const int* __restrict__ labels, const int* __restrict__ base,
                        int* __restrict__ perm){
    int t = threadIdx.x;
    if (t >= 8) return;
    int ch = blockIdx.x;
    int pos = base[ch*8+t];
    int s = ch*CHUNK;
    for (int i=0;i<CHUNK;i++){
        if (labels[s+i] == t) perm[pos++] = s+i;
    }
}

__global__ __launch_bounds__(256) void k_gather(const float* __restrict__ src,
        const int* __restrict__ perm, const int* __restrict__ offPad,
        const int* __restrict__ cnt, float* __restrict__ dst){
    __shared__ int so[9], sc[8];
    int t = threadIdx.x;
    if (t < 9) so[t] = offPad[t];
    if (t < 8) sc[t] = cnt[t];
    __syncthreads();
    int c = blockIdx.y;
    int i = blockIdx.x*256 + t;
    float v = 0.0f;
    if (i < so[8]){
        int k = 0;
        while (k < 7 && i >= so[k+1]) k++;
        int rel = i - so[k];
        if (rel < sc[k]) v = src[(size_t)c*WH + perm[i]];
    }
    dst[(size_t)c*CAP + i] = v;
}

// ---------- per-cluster sums / means ----------

template<bool DIV_N>
__global__ __launch_bounds__(256) void k_segsum(const float* __restrict__ X,
        const int* __restrict__ offPad, const int* __restrict__ cnt,
        float* __restrict__ out){
    int k = blockIdx.x;
    int c = blockIdx.y*32 + (threadIdx.x >> 3);
    int s = threadIdx.x & 7;
    int off = offPad[k], n = cnt[k];
    const float* row = X + (size_t)c*CAP + off;
    float acc = 0.0f;
    for (int j=s; j<n; j+=8) acc += row[j];
    for (int d=1; d<8; d<<=1) acc += __shfl_xor(acc, d);
    if (s == 0) out[k*C_DIM + c] = DIV_N ? acc/(float)n : acc;
}

__global__ __launch_bounds__(256) void k_style_mean(const float* __restrict__ scores,
        const int* __restrict__ cntS, const float* __restrict__ ssum,
        float* __restrict__ total, float* __restrict__ smean){
    int t = threadIdx.x;
    __shared__ float tot[8];
    if (t < 8){
        float s = 0.0f;
        for (int j=0;j<8;j++) s += scores[t*8+j]*(float)cntS[j];
        tot[t] = s; total[t] = s;
    }
    __syncthreads();
    for (int idx=t; idx<8*C_DIM; idx+=256){
        int k = idx / C_DIM, c = idx % C_DIM;
        float s = 0.0f;
        for (int j=0;j<8;j++) s += scores[k*8+j]*ssum[j*C_DIM+c];
        smean[idx] = s / tot[k];
    }
}

// ---------- segment SYRK (fp32): content centered + eps; style raw S2 ----------

template<bool CONTENT>
__global__ __launch_bounds__(256) void k_syrk(const float* __restrict__ X,
        const int* __restrict__ offPad, const int* __restrict__ cnt,
        const float* __restrict__ mean, float* __restrict__ out){
    __shared__ __align__(16) float AsI[16][132];
    __shared__ __align__(16) float AsJ[16][132];
    __shared__ float mI[128], mJ[128];
    int k = blockIdx.z;
    int i0 = blockIdx.y*128, j0 = blockIdx.x*128;
    int t = threadIdx.x;
    int tx = t & 15, ty = t >> 4;
    int off = offPad[k];
    int npad = offPad[k+1] - off;
    int n = cnt[k];
    if (CONTENT){
        if (t < 128) mI[t] = mean[k*C_DIM + i0 + t];
        else mJ[t-128] = mean[k*C_DIM + j0 + (t-128)];
    }
    __syncthreads();
    float acc[8][8] = {};
    const float* Xoff = X + off;
    for (int p=0; p<npad; p+=16){
        #pragma unroll
        for (int q=t; q<512; q+=256){
            int row = q>>2, kq = q&3;
            int pp = p + kq*4;
            float4 v = *(const float4*)&Xoff[(size_t)(i0+row)*CAP + pp];
            if (CONTENT){
                float m = mI[row];
                v.x = (pp+0 < n) ? (v.x - m) : 0.0f;
                v.y = (pp+1 < n) ? (v.y - m) : 0.0f;
                v.z = (pp+2 < n) ? (v.z - m) : 0.0f;
                v.w = (pp+3 < n) ? (v.w - m) : 0.0f;
            }
            AsI[kq*4+0][row]=v.x; AsI[kq*4+1][row]=v.y;
            AsI[kq*4+2][row]=v.z; AsI[kq*4+3][row]=v.w;
        }
        #pragma unroll
        for (int q=t; q<512; q+=256){
            int row = q>>2, kq = q&3;
            int pp = p + kq*4;
            float4 v = *(const float4*)&Xoff[(size_t)(j0+row)*CAP + pp];
            if (CONTENT){
                float m = mJ[row];
                v.x = (pp+0 < n) ? (v.x - m) : 0.0f;
                v.y = (pp+1 < n) ? (v.y - m) : 0.0f;
                v.z = (pp+2 < n) ? (v.z - m) : 0.0f;
                v.w = (pp+3 < n) ? (v.w - m) : 0.0f;
            }
            AsJ[kq*4+0][row]=v.x; AsJ[kq*4+1][row]=v.y;
            AsJ[kq*4+2][row]=v.z; AsJ[kq*4+3][row]=v.w;
        }
        __syncthreads();
        #pragma unroll
        for (int kk=0; kk<16; kk++){
            float a[8], b[8];
            *(float4*)&a[0] = *(const float4*)&AsI[kk][ty*8];
            *(float4*)&a[4] = *(const float4*)&AsI[kk][ty*8+4];
            *(float4*)&b[0] = *(const float4*)&AsJ[kk][tx*8];
            *(float4*)&b[4] = *(const float4*)&AsJ[kk][tx*8+4];
            #pragma unroll
            for (int ii=0; ii<8; ii++)
                #pragma unroll
                for (int jj=0; jj<8; jj++)
                    acc[ii][jj] = fmaf(a[ii], b[jj], acc[ii][jj]);
        }
        __syncthreads();
    }
    float scale = CONTENT ? 1.0f/((float)n - 1.0f) : 1.0f;
    float* O = out + (size_t)k*MSZ;
    for (int ii=0; ii<8; ii++){
        int gi = i0 + ty*8 + ii;
        for (int jj=0; jj<8; jj++){
            int gj = j0 + tx*8 + jj;
            float v = acc[ii][jj]*scale;
            if (CONTENT && gi == gj) v += EPS_C;
            O[(size_t)gi*C_DIM + gj] = v;
        }
    }
}

// ---------- style A assembly ----------

__global__ __launch_bounds__(256) void k_style_A(const float* __restrict__ S2,
        const float* __restrict__ scores, const float* __restrict__ total,
        const float* __restrict__ smean, float* __restrict__ Aout){
    int k = blockIdx.y;
    int e = blockIdx.x*256 + threadIdx.x;
    int i = e >> 9, j = e & 511;
    float s = 0.0f;
    #pragma unroll
    for (int jj=0;jj<8;jj++) s += scores[k*8+jj]*S2[(size_t)jj*MSZ + e];
    float tot = total[k];
    Aout[(size_t)k*MSZ + e] = (s - tot*smean[k*C_DIM+i]*smean[k*C_DIM+j]) / (tot - 1.0f);
}

// ---------- ||A||_1 bound for lambda_max (t >= lambda_max guaranteed) ----------

__global__ __launch_bounds__(256) void k_norm1(const float* __restrict__ A,
                                               float* __restrict__ tvals){
    int mat = blockIdx.x;
    const float* M = A + (size_t)mat*MSZ;
    int wave = threadIdx.x >> 6, lane = threadIdx.x & 63;
    float mx = 0.0f;
    for (int r = wave; r < 512; r += 4){
        const float4* row = (const float4*)(M + (size_t)r*512);
        float s = 0.0f;
        #pragma unroll
        for (int c = 0; c < 2; ++c){
            float4 v = row[lane + c*64];
            s += fabsf(v.x)+fabsf(v.y)+fabsf(v.z)+fabsf(v.w);
        }
        for (int d=1; d<64; d<<=1) s += __shfl_xor(s, d);
        mx = fmaxf(mx, s);
    }
    __shared__ float red[4];
    if (lane == 0) red[wave] = mx;
    __syncthreads();
    if (threadIdx.x == 0)
        tvals[mat] = fmaxf(fmaxf(red[0],red[1]), fmaxf(red[2],red[3]));
}

// ---------- split fp32 -> (hi,lo) bf16 planes; init Z = I ----------

__global__ __launch_bounds__(256) void k_split_init(const float* __restrict__ A,
        const float* __restrict__ tvals, ushort* __restrict__ Y,
        ushort* __restrict__ Z){
    int mat = blockIdx.y;
    int e = blockIdx.x*256 + threadIdx.x;
    float inv = 1.0f / tvals[mat];
    float a = A[(size_t)mat*MSZ + e] * inv;
    unsigned u = __float_as_uint(a);
    ushort hi = (ushort)(u >> 16);
    float r = a - __uint_as_float(u & 0xffff0000u);
    ushort lo = (ushort)(__float_as_uint(r) >> 16);
    size_t base = (size_t)mat*2*MSZ;
    Y[base + e] = hi;
    Y[base + MSZ + e] = lo;
    int i = e >> 9, j = e & 511;
    Z[base + e] = (i==j) ? (ushort)0x3F80 : (ushort)0;
    Z[base + MSZ + e] = 0;
}

// ---------- batched 512^3 split-bf16 MFMA matmul: C = A * B^T (B symmetric) ----------
// EPI 0: split write; EPI 1: q(X)=1.5I-0.5X then split write; EPI 2: fp32 write

template<int EPI>
__global__ __launch_bounds__(256,2) void k_mm_mfma(
        const ushort* __restrict__ A, const ushort* __restrict__ B,
        ushort* __restrict__ Co, float* __restrict__ Cf){
    __shared__ ushort As[2][128*64];
    __shared__ ushort Bs[2][128*64];
    int mat = blockIdx.x;
    int tile = blockIdx.y;
    int i0 = (tile>>2)*128, j0 = (tile&3)*128;
    const ushort* Am = A + (size_t)mat*2*MSZ;
    const ushort* Bm = B + (size_t)mat*2*MSZ;
    int t = threadIdx.x;
    int lane = t & 63, wave = t >> 6;
    int wm = wave >> 1, wn = wave & 1;
    int lr = lane & 15, lk = lane >> 4;
    f32x4 zero = {0.f,0.f,0.f,0.f};
    f32x4 acc[4][4];
    #pragma unroll
    for (int m=0;m<4;m++)
        #pragma unroll
        for (int n=0;n<4;n++) acc[m][n] = zero;
    for (int kb = 0; kb < 8; ++kb){
        int k0 = kb*64;
        #pragma unroll
        for (int p = 0; p < 2; ++p){
            const ushort* Ap = Am + (size_t)p*MSZ;
            const ushort* Bp = Bm + (size_t)p*MSZ;
            #pragma unroll
            for (int i = 0; i < 4; ++i){
                int slot = t + i*256;
                int row = slot >> 3, c8 = slot & 7;
                int swz = (row*64 + c8*8) ^ ((row&7)<<3);
                uint4 va = *(const uint4*)&Ap[(size_t)(i0+row)*512 + k0 + c8*8];
                *(uint4*)&As[p][swz] = va;
                uint4 vb = *(const uint4*)&Bp[(size_t)(j0+row)*512 + k0 + c8*8];
                *(uint4*)&Bs[p][swz] = vb;
            }
        }
        __syncthreads();
        #pragma unroll
        for (int kk = 0; kk < 64; kk += 32){
            bfrag ah[4], al[4], bh[4], bl[4];
            #pragma unroll
            for (int m = 0; m < 4; ++m){
                int row = wm*64 + m*16 + lr;
                int off = (row*64 + kk + lk*8) ^ ((row&7)<<3);
                ah[m] = *(const bfrag*)&As[0][off];
                al[m] = *(const bfrag*)&As[1][off];
            }
            #pragma unroll
            for (int n = 0; n < 4; ++n){
                int row = wn*64 + n*16 + lr;
                int off = (row*64 + kk + lk*8) ^ ((row&7)<<3);
                bh[n] = *(const bfrag*)&Bs[0][off];
                bl[n] = *(const bfrag*)&Bs[1][off];
            }
            #pragma unroll
            for (int m = 0; m < 4; ++m)
                #pragma unroll
                for (int n = 0; n < 4; ++n){
                    acc[m][n] = __builtin_amdgcn_mfma_f32_16x16x32_bf16(ah[m], bh[n], acc[m][n], 0,0,0);
                    acc[m][n] = __builtin_amdgcn_mfma_f32_16x16x32_bf16(ah[m], bl[n], acc[m][n], 0,0,0);
                    acc[m][n] = __builtin_amdgcn_mfma_f32_16x16x32_bf16(al[m], bh[n], acc[m][n], 0,0,0);
                }
        }
        __syncthreads();
    }
    if (EPI == 2){
        float* Cm = Cf + (size_t)mat*MSZ;
        #pragma unroll
        for (int m=0;m<4;m++)
            #pragma unroll
            for (int n=0;n<4;n++)
                #pragma unroll
                for (int j=0;j<4;j++){
                    int gr = i0 + wm*64 + m*16 + lk*4 + j;
                    int gc = j0 + wn*64 + n*16 + lr;
                    Cm[(size_t)gr*512 + gc] = acc[m][n][j];
                }
    } else {
        ushort* Ch = Co + (size_t)mat*2*MSZ;
        ushort* Cl = Ch + MSZ;
        #pragma unroll
        for (int m=0;m<4;m++)
            #pragma unroll
            for (int n=0;n<4;n++)
                #pragma unroll
                for (int j=0;j<4;j++){
                    int gr = i0 + wm*64 + m*16 + lk*4 + j;
                    int gc = j0 + wn*64 + n*16 + lr;
                    float v = acc[m][n][j];
                    if (EPI == 1) v = ((gr==gc)?1.5f:0.0f) - 0.5f*v;
                    unsigned u = __float_as_uint(v);
                    size_t idx = (size_t)gr*512 + gc;
                    Ch[idx] = (ushort)(u >> 16);
                    float r = v - __uint_as_float(u & 0xffff0000u);
                    Cl[idx] = (ushort)(__float_as_uint(r) >> 16);
                }
    }
}

// ---------- bias vector: vvec = alpha*smean - alpha*sqrt(ts/tc)*(T cmean) ----------

__global__ __launch_bounds__(256) void k_buildV(const float* __restrict__ T,
        const float* __restrict__ tvals, const float* __restrict__ cmean,
        const float* __restrict__ smean, float* __restrict__ vvec){
    __shared__ float cm[512];
    int k = blockIdx.x, t = threadIdx.x;
    cm[t] = cmean[k*C_DIM + t];
    cm[t+256] = cmean[k*C_DIM + t + 256];
    __syncthreads();
    float scale = ALPHA_C * sqrtf(tvals[8+k]/tvals[k]);
    for (int c=t; c<C_DIM; c+=256){
        const float* row = T + (size_t)k*MSZ + (size_t)c*C_DIM;
        float s = 0.0f;
        for (int d=0; d<C_DIM; d++) s = fmaf(row[d], cm[d], s);
        vvec[k*C_DIM + c] = ALPHA_C*smean[k*C_DIM + c] - scale*s;
    }
}

// ---------- apply affine + scatter (M built on the fly from T) ----------

__global__ __launch_bounds__(256) void k_apply(const float* __restrict__ T,
        const float* __restrict__ tvals, const float* __restrict__ Xc,
        const float* __restrict__ vvec, const int* __restrict__ offPad,
        const int* __restrict__ cnt, const int* __restrict__ perm,
        float* __restrict__ out){
    __shared__ __align__(16) float As[16][132];
    __shared__ __align__(16) float Bs[16][132];
    __shared__ int so[9], scn[8];
    int t = threadIdx.x;
    if (t < 9) so[t] = offPad[t];
    if (t < 8) scn[t] = cnt[t];
    __syncthreads();
    int j0 = blockIdx.x*128;
    if (j0 >= so[8]) return;
    int k = 0;
    while (k < 7 && j0 >= so[k+1]) k++;
    int i0 = blockIdx.y*128;
    const float* Tk = T + (size_t)k*MSZ;
    float ascale = ALPHA_C * sqrtf(tvals[8+k]/tvals[k]);
    int tx = t & 15, ty = t >> 4;
    float acc[8][8] = {};
    for (int k0=0; k0<512; k0+=16){
        #pragma unroll
        for (int q=t; q<512; q+=256){
            int row = q>>2, kq = q&3;
            int gr = i0 + row, gc = k0 + kq*4;
            float4 v = *(const float4*)&Tk[(size_t)gr*512 + gc];
            v.x = v.x*ascale + ((gr==gc+0)?(1.0f-ALPHA_C):0.0f);
            v.y = v.y*ascale + ((gr==gc+1)?(1.0f-ALPHA_C):0.0f);
            v.z = v.z*ascale + ((gr==gc+2)?(1.0f-ALPHA_C):0.0f);
            v.w = v.w*ascale + ((gr==gc+3)?(1.0f-ALPHA_C):0.0f);
            As[kq*4+0][row]=v.x; As[kq*4+1][row]=v.y;
            As[kq*4+2][row]=v.z; As[kq*4+3][row]=v.w;
        }
        #pragma unroll
        for (int q=t; q<512; q+=256){
            int kr = q>>5, nq = q&31;
            float4 v = *(const float4*)&Xc[(size_t)(k0+kr)*CAP + j0 + nq*4];
            *(float4*)&Bs[kr][nq*4] = v;
        }
        __syncthreads();
        #pragma unroll
        for (int kk=0; kk<16; kk++){
            float a[8], b[8];
            *(float4*)&a[0] = *(const float4*)&As[kk][ty*8];
            *(float4*)&a[4] = *(const float4*)&As[kk][ty*8+4];
            *(float4*)&b[0] = *(const float4*)&Bs[kk][tx*8];
            *(float4*)&b[4] = *(const float4*)&Bs[kk][tx*8+4];
            #pragma unroll
            for (int ii=0; ii<8; ii++)
                #pragma unroll
                for (int jj=0; jj<8; jj++)
                    acc[ii][jj] = fmaf(a[ii], b[jj], acc[ii][jj]);
        }
        __syncthreads();
    }
    int rel0 = j0 - so[k];
    int n = scn[k];
    for (int ii=0; ii<8; ii++){
        int gi = i0 + ty*8 + ii;
        float vb = vvec[k*C_DIM + gi];
        for (int jj=0; jj<8; jj++){
            int rel = rel0 + tx*8 + jj;
            if (rel < n){
                int p = perm[j0 + tx*8 + jj];
                out[(size_t)gi*WH + p] = acc[ii][jj] + vb;
            }
        }
    }
}

// ---------- host ----------

extern "C" void kernel_launch(void* const* d_in, const int* in_sizes, int n_in,
                              void* d_out, int out_size, void* d_ws, size_t ws_size,
                              hipStream_t stream) {
    (void)in_sizes; (void)n_in;
    const float* cf     = (const float*)d_in[0];
    const float* sf     = (const float*)d_in[1];
    const float* scores = (const float*)d_in[2];
    const int*   cl     = (const int*)d_in[3];
    const int*   sl     = (const int*)d_in[4];
    float* out = (float*)d_out;
    float* ws  = (float*)d_ws;

    size_t o = 0;
    float* Xc = ws + o; o += (size_t)C_DIM*CAP;
    float* Xs = ws + o; o += (size_t)C_DIM*CAP;
    float* Af = ws + o; o += (size_t)NMAT*MSZ;     // fp32 A; later T (first 8 mats)
    float* Bf0 = ws + o; o += (size_t)NMAT*MSZ;    // split buffers (ushort view)
    float* Bf1 = ws + o; o += (size_t)NMAT*MSZ;
    float* Bf2 = ws + o; o += (size_t)NMAT*MSZ;
    float* Bf3 = ws + o; o += (size_t)NMAT*MSZ;
    float* cmean = ws + o; o += 8*C_DIM;
    float* ssum  = ws + o; o += 8*C_DIM;
    float* smean = ws + o; o += 8*C_DIM;
    float* vvec  = ws + o; o += 8*C_DIM;
    float* tvals = ws + o; o += 16;
    float* total = ws + o; o += 8;
    int* ip = (int*)(ws + o);
    int* permC = ip; ip += CAP;
    int* permS = ip; ip += CAP;
    int* cntC  = ip; ip += 8;
    int* cntS  = ip; ip += 8;
    int* offC  = ip; ip += 9;
    int* offS  = ip; ip += 9;
    int* chC   = ip; ip += NCHUNK*8;
    int* chS   = ip; ip += NCHUNK*8;
    int* baseC = ip; ip += NCHUNK*8;
    int* baseS = ip; ip += NCHUNK*8;
    size_t need_bytes = (size_t)((char*)ip - (char*)d_ws);
    if (ws_size < need_bytes){
        hipMemcpyAsync(d_out, (const void*)cf, (size_t)out_size*sizeof(float),
                       hipMemcpyDeviceToDevice, stream);
        return;
    }
    float* S2f = Bf2;               // dead once style_A consumed; Pq written later
    float* Tf  = Af;                // T reuses A space (first 8 mats)
    ushort* bY = (ushort*)Bf0;
    ushort* bZ = (ushort*)Bf1;
    ushort* bP = (ushort*)Bf2;
    ushort* bS = (ushort*)Bf3;

    k_chunk_hist<<<NCHUNK,256,0,stream>>>(cl, chC);
    k_chunk_hist<<<NCHUNK,256,0,stream>>>(sl, chS);
    k_scan<<<1,64,0,stream>>>(chC, cntC, offC, baseC);
    k_scan<<<1,64,0,stream>>>(chS, cntS, offS, baseS);
    k_place<<<NCHUNK,64,0,stream>>>(cl, baseC, permC);
    k_place<<<NCHUNK,64,0,stream>>>(sl, baseS, permS);

    dim3 gg(CAP/256, C_DIM);
    k_gather<<<gg,256,0,stream>>>(cf, permC, offC, cntC, Xc);
    k_gather<<<gg,256,0,stream>>>(sf, permS, offS, cntS, Xs);

    k_segsum<true><<<dim3(8,16),256,0,stream>>>(Xc, offC, cntC, cmean);
    k_segsum<false><<<dim3(8,16),256,0,stream>>>(Xs, offS, cntS, ssum);
    k_style_mean<<<1,256,0,stream>>>(scores, cntS, ssum, total, smean);

    k_syrk<true><<<dim3(4,4,8),256,0,stream>>>(Xc, offC, cntC, cmean, Af);
    k_syrk<false><<<dim3(4,4,8),256,0,stream>>>(Xs, offS, cntS, nullptr, S2f);
    k_style_A<<<dim3(MSZ/256,8),256,0,stream>>>(S2f, scores, total, smean, Af + (size_t)8*MSZ);

    k_norm1<<<NMAT,256,0,stream>>>(Af, tvals);
    k_split_init<<<dim3(MSZ/256,NMAT),256,0,stream>>>(Af, tvals, bY, bZ);

    for (int it=0; it<NIT; ++it){
        k_mm_mfma<1><<<dim3(NMAT,16),256,0,stream>>>(bZ, bY, bP, nullptr);  // Pq = q(Z*Y)
        k_mm_mfma<0><<<dim3(NMAT,16),256,0,stream>>>(bY, bP, bS, nullptr);  // Ynew = Y*Pq
        k_mm_mfma<0><<<dim3(NMAT,16),256,0,stream>>>(bP, bZ, bY, nullptr);  // Znew = Pq*Z (into old Y)
        ushort* t1 = bY; bY = bS; bS = bZ; bZ = t1;
    }
    // T[k] = Y_style[8+k] * Z_content[k]  (both symmetric), fp32 out
    k_mm_mfma<2><<<dim3(8,16),256,0,stream>>>(bY + (size_t)8*2*MSZ, bZ, nullptr, Tf);

    k_buildV<<<8,256,0,stream>>>(Tf, tvals, cmean, smean, vvec);

    k_apply<<<dim3(CAP/128,4),256,0,stream>>>(Tf, tvals, Xc, vvec, offC, cntC, permC, out);
}

// Round 3
// 1306.562 us; speedup vs baseline: 3.5689x; 1.6172x over previous
//
#include <hip/hip_runtime.h>
#include <math.h>

#define C_DIM 512
#define WH    16384
#define CAP   17408      // 16384 + 8*128 worst-case padding
#define SEG_ALIGN 128
#define NCHUNK 64
#define CHUNK  256
#define NMAT 16
#define NSLICE 4
#define MSZ  (C_DIM*C_DIM)
#define ALPHA_C 0.8f
#define EPS_C   1e-6f
#define NIT 13

typedef __attribute__((ext_vector_type(8))) __bf16 bfrag;
typedef __attribute__((ext_vector_type(4))) float f32x4;

__device__ inline float bf2f(ushort h){ return __uint_as_float(((unsigned)h)<<16); }
__device__ inline void split2(float v, ushort& h, ushort& l){
    unsigned u = __float_as_uint(v);
    h = (ushort)(u >> 16);
    float r = v - __uint_as_float(u & 0xffff0000u);
    l = (ushort)(__float_as_uint(r) >> 16);
}

// shared MFMA inner block: 128x128 tile, K=64 step, split-3 products
#define MFMA_TILE_BLOCK(As0, As1, Bs0, Bs1) \
do { \
    _Pragma("unroll") \
    for (int kk = 0; kk < 64; kk += 32){ \
        bfrag ah[4], al[4], bh[4], bl[4]; \
        _Pragma("unroll") \
        for (int m_ = 0; m_ < 4; ++m_){ \
            int row_ = wm*64 + m_*16 + lr; \
            int off_ = (row_*64 + kk + lk*8) ^ ((row_&7)<<3); \
            ah[m_] = *(const bfrag*)&(As0)[off_]; \
            al[m_] = *(const bfrag*)&(As1)[off_]; \
        } \
        _Pragma("unroll") \
        for (int n_ = 0; n_ < 4; ++n_){ \
            int row_ = wn*64 + n_*16 + lr; \
            int off_ = (row_*64 + kk + lk*8) ^ ((row_&7)<<3); \
            bh[n_] = *(const bfrag*)&(Bs0)[off_]; \
            bl[n_] = *(const bfrag*)&(Bs1)[off_]; \
        } \
        _Pragma("unroll") \
        for (int m_ = 0; m_ < 4; ++m_) \
            _Pragma("unroll") \
            for (int n_ = 0; n_ < 4; ++n_){ \
                acc[m_][n_] = __builtin_amdgcn_mfma_f32_16x16x32_bf16(ah[m_], bh[n_], acc[m_][n_], 0,0,0); \
                acc[m_][n_] = __builtin_amdgcn_mfma_f32_16x16x32_bf16(ah[m_], bl[n_], acc[m_][n_], 0,0,0); \
                acc[m_][n_] = __builtin_amdgcn_mfma_f32_16x16x32_bf16(al[m_], bh[n_], acc[m_][n_], 0,0,0); \
            } \
    } \
} while(0)

// ---------- label bookkeeping (deterministic counting sort) ----------

__global__ __launch_bounds__(256) void k_chunk_hist(const int* __restrict__ labels,
                                                    int* __restrict__ chunkCnt){
    __shared__ int h[8];
    int t = threadIdx.x;
    if (t < 8) h[t] = 0;
    __syncthreads();
    int l = labels[blockIdx.x*CHUNK + t];
    atomicAdd(&h[l], 1);
    __syncthreads();
    if (t < 8) chunkCnt[blockIdx.x*8 + t] = h[t];
}

__global__ void k_scan(const int* __restrict__ chunkCnt, int* __restrict__ cnt,
                       int* __restrict__ offPad, int* __restrict__ base){
    if (threadIdx.x != 0) return;
    int c[8];
    for (int k=0;k<8;k++) c[k]=0;
    for (int ch=0; ch<NCHUNK; ch++)
        for (int k=0;k<8;k++) c[k] += chunkCnt[ch*8+k];
    int off = 0;
    for (int k=0;k<8;k++){
        cnt[k] = c[k];
        offPad[k] = off;
        off += ((c[k] + SEG_ALIGN - 1)/SEG_ALIGN)*SEG_ALIGN;
    }
    offPad[8] = off;
    for (int k=0;k<8;k++){
        int run = offPad[k];
        for (int ch=0; ch<NCHUNK; ch++){
            base[ch*8+k] = run;
            run += chunkCnt[ch*8+k];
        }
    }
}

__global__ void k_place(const int* __restrict__ labels, const int* __restrict__ base,
                        int* __restrict__ perm){
    int t = threadIdx.x;
    if (t >= 8) return;
    int ch = blockIdx.x;
    int pos = base[ch*8+t];
    int s = ch*CHUNK;
    for (int i=0;i<CHUNK;i++){
        if (labels[s+i] == t) perm[pos++] = s+i;
    }
}

// ---------- gather into padded segments, split to bf16 hi/lo planes ----------

__global__ __launch_bounds__(256) void k_gather(const float* __restrict__ src,
        const int* __restrict__ perm, const int* __restrict__ offPad,
        const int* __restrict__ cnt, ushort* __restrict__ dstH,
        ushort* __restrict__ dstL){
    __shared__ int so[9], sc[8];
    int t = threadIdx.x;
    if (t < 9) so[t] = offPad[t];
    if (t < 8) sc[t] = cnt[t];
    __syncthreads();
    int c = blockIdx.y;
    int i = blockIdx.x*256 + t;
    float v = 0.0f;
    if (i < so[8]){
        int k = 0;
        while (k < 7 && i >= so[k+1]) k++;
        int rel = i - so[k];
        if (rel < sc[k]) v = src[(size_t)c*WH + perm[i]];
    }
    ushort h,l; split2(v,h,l);
    dstH[(size_t)c*CAP + i] = h;
    dstL[(size_t)c*CAP + i] = l;
}

// ---------- transpose plane: [512][CAP] -> [CAP][512] (both planes via grid.z) ----------

__global__ __launch_bounds__(256) void k_transpose(const ushort* __restrict__ S,
                                                   ushort* __restrict__ D){
    __shared__ ushort tile[64][72];
    int p = blockIdx.z;
    const ushort* Sp = S + (size_t)p*C_DIM*CAP;
    ushort* Dp = D + (size_t)p*CAP*C_DIM;
    int cb = blockIdx.x*64;   // pixel block
    int rb = blockIdx.y*64;   // channel block
    int t = threadIdx.x;
    int tr = t >> 3, tc = t & 7;
    #pragma unroll
    for (int i=0;i<2;i++){
        int r = tr + i*32;
        uint4 v = *(const uint4*)&Sp[(size_t)(rb+r)*CAP + cb + tc*8];
        ushort* u = (ushort*)&v;
        #pragma unroll
        for (int j=0;j<8;j++) tile[tc*8+j][r] = u[j];
    }
    __syncthreads();
    #pragma unroll
    for (int i=0;i<2;i++){
        int r = tr + i*32;
        uint4 v;
        ushort* u = (ushort*)&v;
        #pragma unroll
        for (int j=0;j<8;j++) u[j] = tile[r][tc*8+j];
        *(uint4*)&Dp[(size_t)(cb+r)*C_DIM + rb + tc*8] = v;
    }
}

// ---------- per-cluster sums / means (from split planes) ----------

template<bool DIV_N>
__global__ __launch_bounds__(256) void k_segsum(const ushort* __restrict__ XH,
        const ushort* __restrict__ XL, const int* __restrict__ offPad,
        const int* __restrict__ cnt, float* __restrict__ out){
    int k = blockIdx.x;
    int c = blockIdx.y*32 + (threadIdx.x >> 3);
    int s = threadIdx.x & 7;
    int off = offPad[k], n = cnt[k];
    const ushort* rh = XH + (size_t)c*CAP + off;
    const ushort* rl = XL + (size_t)c*CAP + off;
    float acc = 0.0f;
    for (int j=s; j<n; j+=8) acc += bf2f(rh[j]) + bf2f(rl[j]);
    for (int d=1; d<8; d<<=1) acc += __shfl_xor(acc, d);
    if (s == 0) out[k*C_DIM + c] = DIV_N ? acc/(float)n : acc;
}

__global__ __launch_bounds__(256) void k_style_mean(const float* __restrict__ scores,
        const int* __restrict__ cntS, const float* __restrict__ ssum,
        float* __restrict__ total, float* __restrict__ smean){
    int t = threadIdx.x;
    __shared__ float tot[8];
    if (t < 8){
        float s = 0.0f;
        for (int j=0;j<8;j++) s += scores[t*8+j]*(float)cntS[j];
        tot[t] = s; total[t] = s;
    }
    __syncthreads();
    for (int idx=t; idx<8*C_DIM; idx+=256){
        int k = idx / C_DIM, c = idx % C_DIM;
        float s = 0.0f;
        for (int j=0;j<8;j++) s += scores[k*8+j]*ssum[j*C_DIM+c];
        smean[idx] = s / tot[k];
    }
}

// ---------- MFMA SYRK: partial S2 = X X^T (raw, uncentered), triangular tiles, split-K ----------

__global__ __launch_bounds__(256,2) void k_syrk_mfma(
        const ushort* __restrict__ Xc, const ushort* __restrict__ Xs,
        const int* __restrict__ offC, const int* __restrict__ offS,
        float* __restrict__ Pf){
    __shared__ ushort As[2][128*64];
    __shared__ ushort Bs[2][128*64];
    int tt = blockIdx.x, slice = blockIdx.y, mat = blockIdx.z;
    int ti, tj;
    if (tt < 4){ ti=0; tj=tt; }
    else if (tt < 7){ ti=1; tj=tt-3; }
    else if (tt < 9){ ti=2; tj=tt-5; }
    else { ti=3; tj=3; }
    const ushort* X = (mat < 8) ? Xc : Xs;
    const int* offP = (mat < 8) ? offC : offS;
    int cl = mat & 7;
    int off = offP[cl], npad = offP[cl+1] - off;
    int i0 = ti*128, j0 = tj*128;
    int L = ((npad + NSLICE*64 - 1)/(NSLICE*64))*64;
    int k_lo = slice*L;
    int k_hi = min(k_lo + L, npad);
    int t = threadIdx.x;
    int lane = t & 63, wave = t >> 6;
    int wm = wave >> 1, wn = wave & 1;
    int lr = lane & 15, lk = lane >> 4;
    f32x4 zero = {0.f,0.f,0.f,0.f};
    f32x4 acc[4][4];
    #pragma unroll
    for (int m=0;m<4;m++)
        #pragma unroll
        for (int n=0;n<4;n++) acc[m][n] = zero;
    for (int k0 = k_lo; k0 < k_hi; k0 += 64){
        #pragma unroll
        for (int p=0;p<2;p++){
            const ushort* Xp = X + (size_t)p*C_DIM*CAP + off + k0;
            #pragma unroll
            for (int i=0;i<4;i++){
                int slot = t + i*256;
                int row = slot >> 3, c8 = slot & 7;
                int swz = (row*64 + c8*8) ^ ((row&7)<<3);
                *(uint4*)&As[p][swz] = *(const uint4*)&Xp[(size_t)(i0+row)*CAP + c8*8];
                *(uint4*)&Bs[p][swz] = *(const uint4*)&Xp[(size_t)(j0+row)*CAP + c8*8];
            }
        }
        __syncthreads();
        MFMA_TILE_BLOCK(As[0], As[1], Bs[0], Bs[1]);
        __syncthreads();
    }
    float* O = Pf + ((size_t)(slice*16 + mat))*MSZ;
    #pragma unroll
    for (int m=0;m<4;m++)
        #pragma unroll
        for (int n=0;n<4;n++)
            #pragma unroll
            for (int j=0;j<4;j++){
                int gr = i0 + wm*64 + m*16 + lk*4 + j;
                int gc = j0 + wn*64 + n*16 + lr;
                O[(size_t)gr*C_DIM + gc] = acc[m][n][j];
            }
}

// ---------- reduce split-K partials: P0 += P1+P2+P3 ----------

__global__ __launch_bounds__(256) void k_reduceP(float* __restrict__ P){
    size_t i = ((size_t)blockIdx.x*256 + threadIdx.x)*4;
    const size_t S = (size_t)NMAT*MSZ;
    float4 a = *(float4*)&P[i];
    float4 b = *(const float4*)&P[i+S];
    float4 c = *(const float4*)&P[i+2*S];
    float4 d = *(const float4*)&P[i+3*S];
    a.x += b.x + c.x + d.x;
    a.y += b.y + c.y + d.y;
    a.z += b.z + c.z + d.z;
    a.w += b.w + c.w + d.w;
    *(float4*)&P[i] = a;
}

// ---------- assemble A (content: centered cov + eps; style: weighted cov) ----------

__global__ __launch_bounds__(256) void k_assemble(const float* __restrict__ P0,
        const float* __restrict__ scores, const float* __restrict__ total,
        const float* __restrict__ cmean, const float* __restrict__ smean,
        const int* __restrict__ cntC, float* __restrict__ Af){
    int mat = blockIdx.y;
    int e = blockIdx.x*256 + threadIdx.x;
    int i = e >> 9, j = e & 511;
    int es = ((i>>7) > (j>>7)) ? (j*C_DIM + i) : e;   // mirror lower tiles from upper
    float v;
    if (mat < 8){
        float n = (float)cntC[mat];
        float s2 = P0[(size_t)mat*MSZ + es];
        v = (s2 - n*cmean[mat*C_DIM+i]*cmean[mat*C_DIM+j])/(n - 1.0f);
        if (i == j) v += EPS_C;
    } else {
        int k = mat - 8;
        float s2 = 0.0f;
        #pragma unroll
        for (int jj=0;jj<8;jj++) s2 += scores[k*8+jj]*P0[(size_t)(8+jj)*MSZ + es];
        float tot = total[k];
        v = (s2 - tot*smean[k*C_DIM+i]*smean[k*C_DIM+j])/(tot - 1.0f);
    }
    Af[(size_t)mat*MSZ + e] = v;
}

// ---------- ||A||_1 bound for lambda_max ----------

__global__ __launch_bounds__(256) void k_norm1(const float* __restrict__ A,
                                               float* __restrict__ tvals){
    int mat = blockIdx.x;
    const float* M = A + (size_t)mat*MSZ;
    int wave = threadIdx.x >> 6, lane = threadIdx.x & 63;
    float mx = 0.0f;
    for (int r = wave; r < 512; r += 4){
        const float4* row = (const float4*)(M + (size_t)r*C_DIM);
        float s = 0.0f;
        #pragma unroll
        for (int c = 0; c < 2; ++c){
            float4 v = row[lane + c*64];
            s += fabsf(v.x)+fabsf(v.y)+fabsf(v.z)+fabsf(v.w);
        }
        for (int d=1; d<64; d<<=1) s += __shfl_xor(s, d);
        mx = fmaxf(mx, s);
    }
    __shared__ float red[4];
    if (lane == 0) red[wave] = mx;
    __syncthreads();
    if (threadIdx.x == 0)
        tvals[mat] = fmaxf(fmaxf(red[0],red[1]), fmaxf(red[2],red[3]));
}

// ---------- split fp32 -> (hi,lo) bf16 planes; init Z = I ----------

__global__ __launch_bounds__(256) void k_split_init(const float* __restrict__ A,
        const float* __restrict__ tvals, ushort* __restrict__ Y,
        ushort* __restrict__ Z){
    int mat = blockIdx.y;
    int e = blockIdx.x*256 + threadIdx.x;
    float inv = 1.0f / tvals[mat];
    float a = A[(size_t)mat*MSZ + e] * inv;
    ushort h,l; split2(a,h,l);
    size_t base = (size_t)mat*2*MSZ;
    Y[base + e] = h;
    Y[base + MSZ + e] = l;
    int i = e >> 9, j = e & 511;
    Z[base + e] = (i==j) ? (ushort)0x3F80 : (ushort)0;
    Z[base + MSZ + e] = 0;
}

// ---------- batched 512^3 split-bf16 MFMA matmul: C = A * B^T (B symmetric) ----------
// EPI 0: split write; EPI 1: q(X)=1.5I-0.5X then split write; EPI 2: fp32 write

template<int EPI>
__global__ __launch_bounds__(256,2) void k_mm_mfma(
        const ushort* __restrict__ A, const ushort* __restrict__ B,
        ushort* __restrict__ Co, float* __restrict__ Cf){
    __shared__ ushort As[2][128*64];
    __shared__ ushort Bs[2][128*64];
    int mat = blockIdx.x;
    int tile = blockIdx.y;
    int i0 = (tile>>2)*128, j0 = (tile&3)*128;
    const ushort* Am = A + (size_t)mat*2*MSZ;
    const ushort* Bm = B + (size_t)mat*2*MSZ;
    int t = threadIdx.x;
    int lane = t & 63, wave = t >> 6;
    int wm = wave >> 1, wn = wave & 1;
    int lr = lane & 15, lk = lane >> 4;
    f32x4 zero = {0.f,0.f,0.f,0.f};
    f32x4 acc[4][4];
    #pragma unroll
    for (int m=0;m<4;m++)
        #pragma unroll
        for (int n=0;n<4;n++) acc[m][n] = zero;
    for (int kb = 0; kb < 8; ++kb){
        int k0 = kb*64;
        #pragma unroll
        for (int p = 0; p < 2; ++p){
            const ushort* Ap = Am + (size_t)p*MSZ;
            const ushort* Bp = Bm + (size_t)p*MSZ;
            #pragma unroll
            for (int i = 0; i < 4; ++i){
                int slot = t + i*256;
                int row = slot >> 3, c8 = slot & 7;
                int swz = (row*64 + c8*8) ^ ((row&7)<<3);
                *(uint4*)&As[p][swz] = *(const uint4*)&Ap[(size_t)(i0+row)*C_DIM + k0 + c8*8];
                *(uint4*)&Bs[p][swz] = *(const uint4*)&Bp[(size_t)(j0+row)*C_DIM + k0 + c8*8];
            }
        }
        __syncthreads();
        MFMA_TILE_BLOCK(As[0], As[1], Bs[0], Bs[1]);
        __syncthreads();
    }
    if (EPI == 2){
        float* Cm = Cf + (size_t)mat*MSZ;
        #pragma unroll
        for (int m=0;m<4;m++)
            #pragma unroll
            for (int n=0;n<4;n++)
                #pragma unroll
                for (int j=0;j<4;j++){
                    int gr = i0 + wm*64 + m*16 + lk*4 + j;
                    int gc = j0 + wn*64 + n*16 + lr;
                    Cm[(size_t)gr*C_DIM + gc] = acc[m][n][j];
                }
    } else {
        ushort* Ch = Co + (size_t)mat*2*MSZ;
        ushort* Cl = Ch + MSZ;
        #pragma unroll
        for (int m=0;m<4;m++)
            #pragma unroll
            for (int n=0;n<4;n++)
                #pragma unroll
                for (int j=0;j<4;j++){
                    int gr = i0 + wm*64 + m*16 + lk*4 + j;
                    int gc = j0 + wn*64 + n*16 + lr;
                    float v = acc[m][n][j];
                    if (EPI == 1) v = ((gr==gc)?1.5f:0.0f) - 0.5f*v;
                    ushort h,l; split2(v,h,l);
                    size_t idx = (size_t)gr*C_DIM + gc;
                    Ch[idx] = h;
                    Cl[idx] = l;
                }
    }
}

// ---------- build split M = ascale*T + (1-alpha)I ----------

__global__ __launch_bounds__(256) void k_buildM(const float* __restrict__ T,
        const float* __restrict__ tvals, ushort* __restrict__ Msp){
    int k = blockIdx.y;
    int e = blockIdx.x*256 + threadIdx.x;
    float scale = ALPHA_C * sqrtf(tvals[8+k]/tvals[k]);
    float v = scale * T[(size_t)k*MSZ + e];
    if ((e>>9) == (e&511)) v += (1.0f - ALPHA_C);
    ushort h,l; split2(v,h,l);
    Msp[(size_t)k*2*MSZ + e] = h;
    Msp[(size_t)k*2*MSZ + MSZ + e] = l;
}

// ---------- bias vector: vvec = alpha*smean - ascale*(T cmean) ----------

__global__ __launch_bounds__(256) void k_buildV(const float* __restrict__ T,
        const float* __restrict__ tvals, const float* __restrict__ cmean,
        const float* __restrict__ smean, float* __restrict__ vvec){
    __shared__ float cm[512];
    int k = blockIdx.x, t = threadIdx.x;
    cm[t] = cmean[k*C_DIM + t];
    cm[t+256] = cmean[k*C_DIM + t + 256];
    __syncthreads();
    float scale = ALPHA_C * sqrtf(tvals[8+k]/tvals[k]);
    int c = blockIdx.y*256 + t;
    const float* row = T + (size_t)k*MSZ + (size_t)c*C_DIM;
    float s = 0.0f;
    for (int d=0; d<C_DIM; d++) s = fmaf(row[d], cm[d], s);
    vvec[k*C_DIM + c] = ALPHA_C*smean[k*C_DIM + c] - scale*s;
}

// ---------- MFMA apply: out = M*Xc + v, scattered through perm ----------

__global__ __launch_bounds__(256,2) void k_apply_mfma(
        const ushort* __restrict__ Msp, const ushort* __restrict__ XT,
        const float* __restrict__ vvec, const int* __restrict__ offPad,
        const int* __restrict__ cnt, const int* __restrict__ perm,
        float* __restrict__ out){
    __shared__ ushort As[2][128*64];
    __shared__ ushort Bs[2][128*64];
    __shared__ int so[9], scn[8];
    int t = threadIdx.x;
    if (t < 9) so[t] = offPad[t];
    if (t < 8) scn[t] = cnt[t];
    __syncthreads();
    int j0 = blockIdx.x*128;
    if (j0 >= so[8]) return;
    int cl = 0;
    while (cl < 7 && j0 >= so[cl+1]) cl++;
    int i0 = blockIdx.y*128;
    const ushort* Am = Msp + (size_t)cl*2*MSZ;
    int lane = t & 63, wave = t >> 6;
    int wm = wave >> 1, wn = wave & 1;
    int lr = lane & 15, lk = lane >> 4;
    f32x4 zero = {0.f,0.f,0.f,0.f};
    f32x4 acc[4][4];
    #pragma unroll
    for (int m=0;m<4;m++)
        #pragma unroll
        for (int n=0;n<4;n++) acc[m][n] = zero;
    for (int kb = 0; kb < 8; ++kb){
        int k0 = kb*64;
        #pragma unroll
        for (int p = 0; p < 2; ++p){
            const ushort* Ap = Am + (size_t)p*MSZ;
            const ushort* Bp = XT + (size_t)p*CAP*C_DIM;
            #pragma unroll
            for (int i = 0; i < 4; ++i){
                int slot = t + i*256;
                int row = slot >> 3, c8 = slot & 7;
                int swz = (row*64 + c8*8) ^ ((row&7)<<3);
                *(uint4*)&As[p][swz] = *(const uint4*)&Ap[(size_t)(i0+row)*C_DIM + k0 + c8*8];
                *(uint4*)&Bs[p][swz] = *(const uint4*)&Bp[(size_t)(j0+row)*C_DIM + k0 + c8*8];
            }
        }
        __syncthreads();
        MFMA_TILE_BLOCK(As[0], As[1], Bs[0], Bs[1]);
        __syncthreads();
    }
    int nk = scn[cl];
    #pragma unroll
    for (int m=0;m<4;m++)
        #pragma unroll
        for (int nn=0;nn<4;nn++)
            #pragma unroll
            for (int j=0;j<4;j++){
                int gr = i0 + wm*64 + m*16 + lk*4 + j;
                int gc = j0 + wn*64 + nn*16 + lr;
                int rel = gc - so[cl];
                if (rel < nk){
                    out[(size_t)gr*WH + perm[gc]] = acc[m][nn][j] + vvec[cl*C_DIM + gr];
                }
            }
}

// ---------- host ----------

extern "C" void kernel_launch(void* const* d_in, const int* in_sizes, int n_in,
                              void* d_out, int out_size, void* d_ws, size_t ws_size,
                              hipStream_t stream) {
    (void)in_sizes; (void)n_in;
    const float* cf     = (const float*)d_in[0];
    const float* sf     = (const float*)d_in[1];
    const float* scores = (const float*)d_in[2];
    const int*   cl     = (const int*)d_in[3];
    const int*   sl     = (const int*)d_in[4];
    float* out = (float*)d_out;
    float* ws  = (float*)d_ws;

    size_t o = 0;
    ushort* XcH = (ushort*)(ws + o); o += (size_t)C_DIM*CAP;   // 2 planes packed
    ushort* XcL = XcH + (size_t)C_DIM*CAP;
    ushort* XsH = (ushort*)(ws + o); o += (size_t)C_DIM*CAP;   // reused as XcT planes
    float* Af  = ws + o; o += (size_t)NMAT*MSZ;                // fp32 A; later T (first 8)
    float* NS0 = ws + o; o += (size_t)4*NMAT*MSZ;              // 4 slots: partials then NS bufs
    float* cmean = ws + o; o += 8*C_DIM;
    float* ssum  = ws + o; o += 8*C_DIM;
    float* smean = ws + o; o += 8*C_DIM;
    float* vvec  = ws + o; o += 8*C_DIM;
    float* tvals = ws + o; o += 16;
    float* total = ws + o; o += 8;
    int* ip = (int*)(ws + o);
    int* permC = ip; ip += CAP;
    int* permS = ip; ip += CAP;
    int* cntC  = ip; ip += 8;
    int* cntS  = ip; ip += 8;
    int* offC  = ip; ip += 9;
    int* offS  = ip; ip += 9;
    int* chC   = ip; ip += NCHUNK*8;
    int* chS   = ip; ip += NCHUNK*8;
    int* baseC = ip; ip += NCHUNK*8;
    int* baseS = ip; ip += NCHUNK*8;
    size_t need_bytes = (size_t)((char*)ip - (char*)d_ws);
    if (ws_size < need_bytes){
        hipMemcpyAsync(d_out, (const void*)cf, (size_t)out_size*sizeof(float),
                       hipMemcpyDeviceToDevice, stream);
        return;
    }
    float* Pf = NS0;                                   // SYRK partials (4 slices)
    float* Tf = Af;                                    // T reuses A space
    ushort* bY = (ushort*)(NS0 + 0*(size_t)NMAT*MSZ);
    ushort* bZ = (ushort*)(NS0 + 1*(size_t)NMAT*MSZ);
    ushort* bP = (ushort*)(NS0 + 2*(size_t)NMAT*MSZ);
    ushort* bS = (ushort*)(NS0 + 3*(size_t)NMAT*MSZ);

    k_chunk_hist<<<NCHUNK,256,0,stream>>>(cl, chC);
    k_chunk_hist<<<NCHUNK,256,0,stream>>>(sl, chS);
    k_scan<<<1,64,0,stream>>>(chC, cntC, offC, baseC);
    k_scan<<<1,64,0,stream>>>(chS, cntS, offS, baseS);
    k_place<<<NCHUNK,64,0,stream>>>(cl, baseC, permC);
    k_place<<<NCHUNK,64,0,stream>>>(sl, baseS, permS);

    dim3 gg(CAP/256, C_DIM);
    k_gather<<<gg,256,0,stream>>>(cf, permC, offC, cntC, XcH, XcL);
    k_gather<<<gg,256,0,stream>>>(sf, permS, offS, cntS, XsH, XsH + (size_t)C_DIM*CAP);

    k_segsum<true><<<dim3(8,16),256,0,stream>>>(XcH, XcL, offC, cntC, cmean);
    k_segsum<false><<<dim3(8,16),256,0,stream>>>(XsH, XsH + (size_t)C_DIM*CAP, offS, cntS, ssum);
    k_style_mean<<<1,256,0,stream>>>(scores, cntS, ssum, total, smean);

    // raw S2 for all 16 (cluster, src) pairs, triangular tiles, split-K=4
    k_syrk_mfma<<<dim3(10,NSLICE,16),256,0,stream>>>(XcH, XsH, offC, offS, Pf);

    // transpose Xc planes into Xs region (Xs fully consumed above)
    k_transpose<<<dim3(CAP/64, C_DIM/64, 2),256,0,stream>>>(XcH, XsH);
    ushort* XT = XsH;

    k_reduceP<<<(NMAT*MSZ)/1024,256,0,stream>>>(Pf);
    k_assemble<<<dim3(MSZ/256,16),256,0,stream>>>(Pf, scores, total, cmean, smean, cntC, Af);

    k_norm1<<<NMAT,256,0,stream>>>(Af, tvals);
    k_split_init<<<dim3(MSZ/256,NMAT),256,0,stream>>>(Af, tvals, bY, bZ);

    for (int it=0; it<NIT; ++it){
        k_mm_mfma<1><<<dim3(NMAT,16),256,0,stream>>>(bZ, bY, bP, nullptr);  // Pq = q(Z*Y)
        k_mm_mfma<0><<<dim3(NMAT,16),256,0,stream>>>(bY, bP, bS, nullptr);  // Ynew = Y*Pq
        k_mm_mfma<0><<<dim3(NMAT,16),256,0,stream>>>(bP, bZ, bY, nullptr);  // Znew = Pq*Z
        ushort* t1 = bY; bY = bS; bS = bZ; bZ = t1;
    }
    // T[k] = Y_style[8+k] * Z_content[k], fp32 out
    k_mm_mfma<2><<<dim3(8,16),256,0,stream>>>(bY + (size_t)8*2*MSZ, bZ, nullptr, Tf);

    ushort* Msp = bP;  // dead slot after NS
    k_buildM<<<dim3(MSZ/256,8),256,0,stream>>>(Tf, tvals, Msp);
    k_buildV<<<dim3(8,2),256,0,stream>>>(Tf, tvals, cmean, smean, vvec);

    k_apply_mfma<<<dim3(CAP/128,4),256,0,stream>>>(Msp, XT, vvec, offC, cntC, permC, out);
}

// Round 4
// 1114.020 us; speedup vs baseline: 4.1857x; 1.1728x over previous
//
#include <hip/hip_runtime.h>
#include <math.h>

#define C_DIM 512
#define WH    16384
#define CAP   17408      // 16384 + 8*128 worst-case padding
#define SEG_ALIGN 128
#define NCHUNK 64
#define CHUNK  256
#define NMAT 16
#define NSLICE 4
#define MSZ  (C_DIM*C_DIM)
#define ALPHA_C 0.8f
#define EPS_C   1e-6f
#define NIT 11

typedef __attribute__((ext_vector_type(8))) __bf16 bfrag;
typedef __attribute__((ext_vector_type(4))) float f32x4;

__device__ inline float bf2f(ushort h){ return __uint_as_float(((unsigned)h)<<16); }
__device__ inline void split2(float v, ushort& h, ushort& l){
    unsigned u = __float_as_uint(v);
    h = (ushort)(u >> 16);
    float r = v - __uint_as_float(u & 0xffff0000u);
    l = (ushort)(__float_as_uint(r) >> 16);
}

// XCD-contiguous chunk swizzle (requires nwg % 8 == 0)
__device__ __forceinline__ int xcd_swz(int bid, int nwg){
    int c = nwg >> 3;
    return (bid & 7)*c + (bid >> 3);
}

// shared MFMA inner block: 128x128 tile, K=64 step, split-3 products
#define MFMA_TILE_BLOCK(As0, As1, Bs0, Bs1) \
do { \
    _Pragma("unroll") \
    for (int kk = 0; kk < 64; kk += 32){ \
        bfrag ah[4], al[4], bh[4], bl[4]; \
        _Pragma("unroll") \
        for (int m_ = 0; m_ < 4; ++m_){ \
            int row_ = wm*64 + m_*16 + lr; \
            int off_ = (row_*64 + kk + lk*8) ^ ((row_&7)<<3); \
            ah[m_] = *(const bfrag*)&(As0)[off_]; \
            al[m_] = *(const bfrag*)&(As1)[off_]; \
        } \
        _Pragma("unroll") \
        for (int n_ = 0; n_ < 4; ++n_){ \
            int row_ = wn*64 + n_*16 + lr; \
            int off_ = (row_*64 + kk + lk*8) ^ ((row_&7)<<3); \
            bh[n_] = *(const bfrag*)&(Bs0)[off_]; \
            bl[n_] = *(const bfrag*)&(Bs1)[off_]; \
        } \
        _Pragma("unroll") \
        for (int m_ = 0; m_ < 4; ++m_) \
            _Pragma("unroll") \
            for (int n_ = 0; n_ < 4; ++n_){ \
                acc[m_][n_] = __builtin_amdgcn_mfma_f32_16x16x32_bf16(ah[m_], bh[n_], acc[m_][n_], 0,0,0); \
                acc[m_][n_] = __builtin_amdgcn_mfma_f32_16x16x32_bf16(ah[m_], bl[n_], acc[m_][n_], 0,0,0); \
                acc[m_][n_] = __builtin_amdgcn_mfma_f32_16x16x32_bf16(al[m_], bh[n_], acc[m_][n_], 0,0,0); \
            } \
    } \
} while(0)

// core K-loop for 512-K matmul on split planes with stride C_DIM
__device__ __forceinline__ void mm_core(const ushort* __restrict__ Am,
        const ushort* __restrict__ Bm, int i0, int j0,
        ushort (&As)[2][8192], ushort (&Bs)[2][8192], f32x4 (&acc)[4][4],
        int wm, int wn, int lr, int lk){
    int t = threadIdx.x;
    for (int kb = 0; kb < 8; ++kb){
        int k0 = kb*64;
        #pragma unroll
        for (int p = 0; p < 2; ++p){
            const ushort* Ap = Am + (size_t)p*MSZ;
            const ushort* Bp = Bm + (size_t)p*MSZ;
            #pragma unroll
            for (int i = 0; i < 4; ++i){
                int slot = t + i*256;
                int row = slot >> 3, c8 = slot & 7;
                int swz = (row*64 + c8*8) ^ ((row&7)<<3);
                *(uint4*)&As[p][swz] = *(const uint4*)&Ap[(size_t)(i0+row)*C_DIM + k0 + c8*8];
                *(uint4*)&Bs[p][swz] = *(const uint4*)&Bp[(size_t)(j0+row)*C_DIM + k0 + c8*8];
            }
        }
        __syncthreads();
        MFMA_TILE_BLOCK(As[0], As[1], Bs[0], Bs[1]);
        __syncthreads();
    }
}

// ---------- label bookkeeping (deterministic counting sort) ----------

__global__ __launch_bounds__(256) void k_chunk_hist(const int* __restrict__ labels,
                                                    int* __restrict__ chunkCnt){
    __shared__ int h[8];
    int t = threadIdx.x;
    if (t < 8) h[t] = 0;
    __syncthreads();
    int l = labels[blockIdx.x*CHUNK + t];
    atomicAdd(&h[l], 1);
    __syncthreads();
    if (t < 8) chunkCnt[blockIdx.x*8 + t] = h[t];
}

__global__ void k_scan(const int* __restrict__ chunkCnt, int* __restrict__ cnt,
                       int* __restrict__ offPad, int* __restrict__ base){
    if (threadIdx.x != 0) return;
    int c[8];
    for (int k=0;k<8;k++) c[k]=0;
    for (int ch=0; ch<NCHUNK; ch++)
        for (int k=0;k<8;k++) c[k] += chunkCnt[ch*8+k];
    int off = 0;
    for (int k=0;k<8;k++){
        cnt[k] = c[k];
        offPad[k] = off;
        off += ((c[k] + SEG_ALIGN - 1)/SEG_ALIGN)*SEG_ALIGN;
    }
    offPad[8] = off;
    for (int k=0;k<8;k++){
        int run = offPad[k];
        for (int ch=0; ch<NCHUNK; ch++){
            base[ch*8+k] = run;
            run += chunkCnt[ch*8+k];
        }
    }
}

__global__ void k_place(const int* __restrict__ labels, const int* __restrict__ base,
                        int* __restrict__ perm, int* __restrict__ inv){
    int t = threadIdx.x;
    if (t >= 8) return;
    int ch = blockIdx.x;
    int pos = base[ch*8+t];
    int s = ch*CHUNK;
    for (int i=0;i<CHUNK;i++){
        if (labels[s+i] == t){
            perm[pos] = s+i;
            if (inv) inv[s+i] = pos;
            pos++;
        }
    }
}

// ---------- gather into padded segments, split to bf16 hi/lo planes ----------

__global__ __launch_bounds__(256) void k_gather(const float* __restrict__ src,
        const int* __restrict__ perm, const int* __restrict__ offPad,
        const int* __restrict__ cnt, ushort* __restrict__ dstH,
        ushort* __restrict__ dstL){
    __shared__ int so[9], sc[8];
    int t = threadIdx.x;
    if (t < 9) so[t] = offPad[t];
    if (t < 8) sc[t] = cnt[t];
    __syncthreads();
    int c = blockIdx.y;
    int i = blockIdx.x*256 + t;
    float v = 0.0f;
    if (i < so[8]){
        int k = 0;
        while (k < 7 && i >= so[k+1]) k++;
        int rel = i - so[k];
        if (rel < sc[k]) v = src[(size_t)c*WH + perm[i]];
    }
    ushort h,l; split2(v,h,l);
    dstH[(size_t)c*CAP + i] = h;
    dstL[(size_t)c*CAP + i] = l;
}

// ---------- transpose plane: [512][CAP] -> [CAP][512] ----------

__global__ __launch_bounds__(256) void k_transpose(const ushort* __restrict__ S,
                                                   ushort* __restrict__ D){
    __shared__ ushort tile[64][72];
    int p = blockIdx.z;
    const ushort* Sp = S + (size_t)p*C_DIM*CAP;
    ushort* Dp = D + (size_t)p*CAP*C_DIM;
    int cb = blockIdx.x*64;   // pixel block
    int rb = blockIdx.y*64;   // channel block
    int t = threadIdx.x;
    int tr = t >> 3, tc = t & 7;
    #pragma unroll
    for (int i=0;i<2;i++){
        int r = tr + i*32;
        uint4 v = *(const uint4*)&Sp[(size_t)(rb+r)*CAP + cb + tc*8];
        ushort* u = (ushort*)&v;
        #pragma unroll
        for (int j=0;j<8;j++) tile[tc*8+j][r] = u[j];
    }
    __syncthreads();
    #pragma unroll
    for (int i=0;i<2;i++){
        int r = tr + i*32;
        uint4 v;
        ushort* u = (ushort*)&v;
        #pragma unroll
        for (int j=0;j<8;j++) u[j] = tile[r][tc*8+j];
        *(uint4*)&Dp[(size_t)(cb+r)*C_DIM + rb + tc*8] = v;
    }
}

// ---------- per-cluster sums / means (from split planes) ----------

template<bool DIV_N>
__global__ __launch_bounds__(256) void k_segsum(const ushort* __restrict__ XH,
        const ushort* __restrict__ XL, const int* __restrict__ offPad,
        const int* __restrict__ cnt, float* __restrict__ out){
    int k = blockIdx.x;
    int c = blockIdx.y*32 + (threadIdx.x >> 3);
    int s = threadIdx.x & 7;
    int off = offPad[k], n = cnt[k];
    const ushort* rh = XH + (size_t)c*CAP + off;
    const ushort* rl = XL + (size_t)c*CAP + off;
    float acc = 0.0f;
    for (int j=s; j<n; j+=8) acc += bf2f(rh[j]) + bf2f(rl[j]);
    for (int d=1; d<8; d<<=1) acc += __shfl_xor(acc, d);
    if (s == 0) out[k*C_DIM + c] = DIV_N ? acc/(float)n : acc;
}

__global__ __launch_bounds__(256) void k_style_mean(const float* __restrict__ scores,
        const int* __restrict__ cntS, const float* __restrict__ ssum,
        float* __restrict__ total, float* __restrict__ smean){
    int t = threadIdx.x;
    __shared__ float tot[8];
    if (t < 8){
        float s = 0.0f;
        for (int j=0;j<8;j++) s += scores[t*8+j]*(float)cntS[j];
        tot[t] = s; total[t] = s;
    }
    __syncthreads();
    for (int idx=t; idx<8*C_DIM; idx+=256){
        int k = idx / C_DIM, c = idx % C_DIM;
        float s = 0.0f;
        for (int j=0;j<8;j++) s += scores[k*8+j]*ssum[j*C_DIM+c];
        smean[idx] = s / tot[k];
    }
}

// ---------- MFMA SYRK: partial S2 = X X^T, triangular tiles, split-K ----------

__global__ __launch_bounds__(256,2) void k_syrk_mfma(
        const ushort* __restrict__ Xc, const ushort* __restrict__ Xs,
        const int* __restrict__ offC, const int* __restrict__ offS,
        float* __restrict__ Pf){
    __shared__ ushort As[2][8192];
    __shared__ ushort Bs[2][8192];
    int wg = xcd_swz(blockIdx.x, NMAT*NSLICE*10);
    int mat = wg / (NSLICE*10);
    int rem = wg % (NSLICE*10);
    int slice = rem / 10, tt = rem % 10;
    int ti, tj;
    if (tt < 4){ ti=0; tj=tt; }
    else if (tt < 7){ ti=1; tj=tt-3; }
    else if (tt < 9){ ti=2; tj=tt-5; }
    else { ti=3; tj=3; }
    const ushort* X = (mat < 8) ? Xc : Xs;
    const int* offP = (mat < 8) ? offC : offS;
    int cl = mat & 7;
    int off = offP[cl], npad = offP[cl+1] - off;
    int i0 = ti*128, j0 = tj*128;
    int L = ((npad + NSLICE*64 - 1)/(NSLICE*64))*64;
    int k_lo = slice*L;
    int k_hi = min(k_lo + L, npad);
    int t = threadIdx.x;
    int lane = t & 63, wave = t >> 6;
    int wm = wave >> 1, wn = wave & 1;
    int lr = lane & 15, lk = lane >> 4;
    f32x4 zero = {0.f,0.f,0.f,0.f};
    f32x4 acc[4][4];
    #pragma unroll
    for (int m=0;m<4;m++)
        #pragma unroll
        for (int n=0;n<4;n++) acc[m][n] = zero;
    for (int k0 = k_lo; k0 < k_hi; k0 += 64){
        #pragma unroll
        for (int p=0;p<2;p++){
            const ushort* Xp = X + (size_t)p*C_DIM*CAP + off + k0;
            #pragma unroll
            for (int i=0;i<4;i++){
                int slot = t + i*256;
                int row = slot >> 3, c8 = slot & 7;
                int swz = (row*64 + c8*8) ^ ((row&7)<<3);
                *(uint4*)&As[p][swz] = *(const uint4*)&Xp[(size_t)(i0+row)*CAP + c8*8];
                *(uint4*)&Bs[p][swz] = *(const uint4*)&Xp[(size_t)(j0+row)*CAP + c8*8];
            }
        }
        __syncthreads();
        MFMA_TILE_BLOCK(As[0], As[1], Bs[0], Bs[1]);
        __syncthreads();
    }
    float* O = Pf + ((size_t)(slice*16 + mat))*MSZ;
    #pragma unroll
    for (int m=0;m<4;m++)
        #pragma unroll
        for (int n=0;n<4;n++)
            #pragma unroll
            for (int j=0;j<4;j++){
                int gr = i0 + wm*64 + m*16 + lk*4 + j;
                int gc = j0 + wn*64 + n*16 + lr;
                O[(size_t)gr*C_DIM + gc] = acc[m][n][j];
            }
}

// ---------- reduce split-K partials: P0 += P1+P2+P3 ----------

__global__ __launch_bounds__(256) void k_reduceP(float* __restrict__ P){
    size_t i = ((size_t)blockIdx.x*256 + threadIdx.x)*4;
    const size_t S = (size_t)NMAT*MSZ;
    float4 a = *(float4*)&P[i];
    float4 b = *(const float4*)&P[i+S];
    float4 c = *(const float4*)&P[i+2*S];
    float4 d = *(const float4*)&P[i+3*S];
    a.x += b.x + c.x + d.x;
    a.y += b.y + c.y + d.y;
    a.z += b.z + c.z + d.z;
    a.w += b.w + c.w + d.w;
    *(float4*)&P[i] = a;
}

// ---------- assemble A (content: centered cov + eps; style: weighted cov) ----------

__global__ __launch_bounds__(256) void k_assemble(const float* __restrict__ P0,
        const float* __restrict__ scores, const float* __restrict__ total,
        const float* __restrict__ cmean, const float* __restrict__ smean,
        const int* __restrict__ cntC, float* __restrict__ Af){
    int mat = blockIdx.y;
    int e = blockIdx.x*256 + threadIdx.x;
    int i = e >> 9, j = e & 511;
    int es = ((i>>7) > (j>>7)) ? (j*C_DIM + i) : e;   // mirror lower tiles from upper
    float v;
    if (mat < 8){
        float n = (float)cntC[mat];
        float s2 = P0[(size_t)mat*MSZ + es];
        v = (s2 - n*cmean[mat*C_DIM+i]*cmean[mat*C_DIM+j])/(n - 1.0f);
        if (i == j) v += EPS_C;
    } else {
        int k = mat - 8;
        float s2 = 0.0f;
        #pragma unroll
        for (int jj=0;jj<8;jj++) s2 += scores[k*8+jj]*P0[(size_t)(8+jj)*MSZ + es];
        float tot = total[k];
        v = (s2 - tot*smean[k*C_DIM+i]*smean[k*C_DIM+j])/(tot - 1.0f);
    }
    Af[(size_t)mat*MSZ + e] = v;
}

// ---------- ||A||_1; MODE 1 also tightens tvals *= sqrt(t2) ----------

template<int MODE>
__global__ __launch_bounds__(256) void k_norm1(const float* __restrict__ A,
        float* __restrict__ tvals, float* __restrict__ t2vals){
    int mat = blockIdx.x;
    const float* M = A + (size_t)mat*MSZ;
    int wave = threadIdx.x >> 6, lane = threadIdx.x & 63;
    float mx = 0.0f;
    for (int r = wave; r < 512; r += 4){
        const float4* row = (const float4*)(M + (size_t)r*C_DIM);
        float s = 0.0f;
        #pragma unroll
        for (int c = 0; c < 2; ++c){
            float4 v = row[lane + c*64];
            s += fabsf(v.x)+fabsf(v.y)+fabsf(v.z)+fabsf(v.w);
        }
        for (int d=1; d<64; d<<=1) s += __shfl_xor(s, d);
        mx = fmaxf(mx, s);
    }
    __shared__ float red[4];
    if (lane == 0) red[wave] = mx;
    __syncthreads();
    if (threadIdx.x == 0){
        float tv = fmaxf(fmaxf(red[0],red[1]), fmaxf(red[2],red[3]));
        if (MODE == 0) tvals[mat] = tv;
        else { t2vals[mat] = tv; tvals[mat] *= sqrtf(tv); }
    }
}

// ---------- split fp32 -> (hi,lo) bf16 planes; init Z = I ----------

__global__ __launch_bounds__(256) void k_split_init(const float* __restrict__ A,
        const float* __restrict__ tvals, ushort* __restrict__ Y,
        ushort* __restrict__ Z){
    int mat = blockIdx.y;
    int e = blockIdx.x*256 + threadIdx.x;
    float inv = 1.0f / tvals[mat];
    float a = A[(size_t)mat*MSZ + e] * inv;
    ushort h,l; split2(a,h,l);
    size_t base = (size_t)mat*2*MSZ;
    Y[base + e] = h;
    Y[base + MSZ + e] = l;
    int i = e >> 9, j = e & 511;
    Z[base + e] = (i==j) ? (ushort)0x3F80 : (ushort)0;
    Z[base + MSZ + e] = 0;
}

// ---------- rescale Y by rsqrt(t2) (tighter spectral normalization) ----------

__global__ __launch_bounds__(256) void k_rescale(ushort* __restrict__ Y,
        const float* __restrict__ t2vals){
    int mat = blockIdx.y;
    int e = blockIdx.x*256 + threadIdx.x;
    float s = rsqrtf(t2vals[mat]);
    size_t base = (size_t)mat*2*MSZ;
    float v = (bf2f(Y[base+e]) + bf2f(Y[base+MSZ+e])) * s;
    ushort h,l; split2(v,h,l);
    Y[base + e] = h;
    Y[base + MSZ + e] = l;
}

// ---------- batched 512^3 split-bf16 MFMA matmul: C = A * B^T (operands symmetric) ----------
// EPI 0: split write; EPI 1: q(X)=1.5I-0.5X then split write; EPI 2: fp32 write

template<int EPI>
__global__ __launch_bounds__(256,2) void k_mm_ns(
        const ushort* __restrict__ A, const ushort* __restrict__ B,
        ushort* __restrict__ Co, float* __restrict__ Cf, int nmat){
    __shared__ ushort As[2][8192];
    __shared__ ushort Bs[2][8192];
    int wg = xcd_swz(blockIdx.x, nmat*16);
    int mat = wg >> 4, tile = wg & 15;
    int i0 = (tile>>2)*128, j0 = (tile&3)*128;
    const ushort* Am = A + (size_t)mat*2*MSZ;
    const ushort* Bm = B + (size_t)mat*2*MSZ;
    int t = threadIdx.x;
    int lane = t & 63, wave = t >> 6;
    int wm = wave >> 1, wn = wave & 1;
    int lr = lane & 15, lk = lane >> 4;
    f32x4 zero = {0.f,0.f,0.f,0.f};
    f32x4 acc[4][4];
    #pragma unroll
    for (int m=0;m<4;m++)
        #pragma unroll
        for (int n=0;n<4;n++) acc[m][n] = zero;
    mm_core(Am, Bm, i0, j0, As, Bs, acc, wm, wn, lr, lk);
    if (EPI == 2){
        float* Cm = Cf + (size_t)mat*MSZ;
        #pragma unroll
        for (int m=0;m<4;m++)
            #pragma unroll
            for (int n=0;n<4;n++)
                #pragma unroll
                for (int j=0;j<4;j++){
                    int gr = i0 + wm*64 + m*16 + lk*4 + j;
                    int gc = j0 + wn*64 + n*16 + lr;
                    Cm[(size_t)gr*C_DIM + gc] = acc[m][n][j];
                }
    } else {
        ushort* Ch = Co + (size_t)mat*2*MSZ;
        ushort* Cl = Ch + MSZ;
        #pragma unroll
        for (int m=0;m<4;m++)
            #pragma unroll
            for (int n=0;n<4;n++)
                #pragma unroll
                for (int j=0;j<4;j++){
                    int gr = i0 + wm*64 + m*16 + lk*4 + j;
                    int gc = j0 + wn*64 + n*16 + lr;
                    float v = acc[m][n][j];
                    if (EPI == 1) v = ((gr==gc)?1.5f:0.0f) - 0.5f*v;
                    ushort h,l; split2(v,h,l);
                    size_t idx = (size_t)gr*C_DIM + gc;
                    Ch[idx] = h;
                    Cl[idx] = l;
                }
    }
}

// ---------- merged NS stage 2: fy = Y*qP, fz = qP*Z (one dispatch, 512 blocks) ----------

__global__ __launch_bounds__(256,2) void k_mm_ns2(
        const ushort* __restrict__ Y, const ushort* __restrict__ P,
        const ushort* __restrict__ Z, ushort* __restrict__ fy,
        ushort* __restrict__ fz){
    __shared__ ushort As[2][8192];
    __shared__ ushort Bs[2][8192];
    int wg = xcd_swz(blockIdx.x, NMAT*32);
    int mat = wg >> 5;
    int r = wg & 31;
    int op = r >> 4, tile = r & 15;
    int i0 = (tile>>2)*128, j0 = (tile&3)*128;
    const ushort* Am = (op ? P : Y) + (size_t)mat*2*MSZ;
    const ushort* Bm = (op ? Z : P) + (size_t)mat*2*MSZ;
    ushort* Ch = (op ? fz : fy) + (size_t)mat*2*MSZ;
    ushort* Cl = Ch + MSZ;
    int t = threadIdx.x;
    int lane = t & 63, wave = t >> 6;
    int wm = wave >> 1, wn = wave & 1;
    int lr = lane & 15, lk = lane >> 4;
    f32x4 zero = {0.f,0.f,0.f,0.f};
    f32x4 acc[4][4];
    #pragma unroll
    for (int m=0;m<4;m++)
        #pragma unroll
        for (int n=0;n<4;n++) acc[m][n] = zero;
    mm_core(Am, Bm, i0, j0, As, Bs, acc, wm, wn, lr, lk);
    #pragma unroll
    for (int m=0;m<4;m++)
        #pragma unroll
        for (int n=0;n<4;n++)
            #pragma unroll
            for (int j=0;j<4;j++){
                int gr = i0 + wm*64 + m*16 + lk*4 + j;
                int gc = j0 + wn*64 + n*16 + lr;
                ushort h,l; split2(acc[m][n][j],h,l);
                size_t idx = (size_t)gr*C_DIM + gc;
                Ch[idx] = h;
                Cl[idx] = l;
            }
}

// ---------- build split M = ascale*T + (1-alpha)I ----------

__global__ __launch_bounds__(256) void k_buildM(const float* __restrict__ T,
        const float* __restrict__ tvals, ushort* __restrict__ Msp){
    int k = blockIdx.y;
    int e = blockIdx.x*256 + threadIdx.x;
    float scale = ALPHA_C * sqrtf(tvals[8+k]/tvals[k]);
    float v = scale * T[(size_t)k*MSZ + e];
    if ((e>>9) == (e&511)) v += (1.0f - ALPHA_C);
    ushort h,l; split2(v,h,l);
    Msp[(size_t)k*2*MSZ + e] = h;
    Msp[(size_t)k*2*MSZ + MSZ + e] = l;
}

// ---------- bias vector: vvec = alpha*smean - ascale*(T cmean) ----------

__global__ __launch_bounds__(256) void k_buildV(const float* __restrict__ T,
        const float* __restrict__ tvals, const float* __restrict__ cmean,
        const float* __restrict__ smean, float* __restrict__ vvec){
    __shared__ float cm[512];
    int k = blockIdx.x, t = threadIdx.x;
    cm[t] = cmean[k*C_DIM + t];
    cm[t+256] = cmean[k*C_DIM + t + 256];
    __syncthreads();
    float scale = ALPHA_C * sqrtf(tvals[8+k]/tvals[k]);
    int c = blockIdx.y*256 + t;
    const float* row = T + (size_t)k*MSZ + (size_t)c*C_DIM;
    float s = 0.0f;
    for (int d=0; d<C_DIM; d++) s = fmaf(row[d], cm[d], s);
    vvec[k*C_DIM + c] = ALPHA_C*smean[k*C_DIM + c] - scale*s;
}

// ---------- MFMA apply: Sg = M*Xc + v in gathered order (coalesced) ----------

__global__ __launch_bounds__(256,2) void k_apply_mfma(
        const ushort* __restrict__ Msp, const ushort* __restrict__ XT,
        const float* __restrict__ vvec, const int* __restrict__ offPad,
        float* __restrict__ Sg){
    __shared__ ushort As[2][8192];
    __shared__ ushort Bs[2][8192];
    __shared__ int so[9];
    int t = threadIdx.x;
    if (t < 9) so[t] = offPad[t];
    __syncthreads();
    int wg = xcd_swz(blockIdx.x, (CAP/128)*4);
    int j0 = (wg>>2)*128;
    int i0 = (wg&3)*128;
    if (j0 >= so[8]) return;
    int cl = 0;
    while (cl < 7 && j0 >= so[cl+1]) cl++;
    const ushort* Am = Msp + (size_t)cl*2*MSZ;
    int lane = t & 63, wave = t >> 6;
    int wm = wave >> 1, wn = wave & 1;
    int lr = lane & 15, lk = lane >> 4;
    f32x4 zero = {0.f,0.f,0.f,0.f};
    f32x4 acc[4][4];
    #pragma unroll
    for (int m=0;m<4;m++)
        #pragma unroll
        for (int n=0;n<4;n++) acc[m][n] = zero;
    for (int kb = 0; kb < 8; ++kb){
        int k0 = kb*64;
        #pragma unroll
        for (int p = 0; p < 2; ++p){
            const ushort* Ap = Am + (size_t)p*MSZ;
            const ushort* Bp = XT + (size_t)p*CAP*C_DIM;
            #pragma unroll
            for (int i = 0; i < 4; ++i){
                int slot = t + i*256;
                int row = slot >> 3, c8 = slot & 7;
                int swz = (row*64 + c8*8) ^ ((row&7)<<3);
                *(uint4*)&As[p][swz] = *(const uint4*)&Ap[(size_t)(i0+row)*C_DIM + k0 + c8*8];
                *(uint4*)&Bs[p][swz] = *(const uint4*)&Bp[(size_t)(j0+row)*C_DIM + k0 + c8*8];
            }
        }
        __syncthreads();
        MFMA_TILE_BLOCK(As[0], As[1], Bs[0], Bs[1]);
        __syncthreads();
    }
    #pragma unroll
    for (int m=0;m<4;m++)
        #pragma unroll
        for (int nn=0;nn<4;nn++)
            #pragma unroll
            for (int j=0;j<4;j++){
                int gr = i0 + wm*64 + m*16 + lk*4 + j;
                int gc = j0 + wn*64 + nn*16 + lr;
                Sg[(size_t)gr*CAP + gc] = acc[m][nn][j] + vvec[cl*C_DIM + gr];
            }
}

// ---------- scatter: out[c][p] = Sg[c][ginv[p]] (coalesced writes) ----------

__global__ __launch_bounds__(256) void k_scatter(const float* __restrict__ Sg,
        const int* __restrict__ ginv, float* __restrict__ out){
    size_t idx = (size_t)blockIdx.x*256 + threadIdx.x;
    int p = (int)(idx & (WH-1));
    int c = (int)(idx >> 14);
    out[idx] = Sg[(size_t)c*CAP + ginv[p]];
}

// ---------- host ----------

extern "C" void kernel_launch(void* const* d_in, const int* in_sizes, int n_in,
                              void* d_out, int out_size, void* d_ws, size_t ws_size,
                              hipStream_t stream) {
    (void)in_sizes; (void)n_in;
    const float* cf     = (const float*)d_in[0];
    const float* sf     = (const float*)d_in[1];
    const float* scores = (const float*)d_in[2];
    const int*   cl     = (const int*)d_in[3];
    const int*   sl     = (const int*)d_in[4];
    float* out = (float*)d_out;
    float* ws  = (float*)d_ws;

    size_t o = 0;
    ushort* XcH = (ushort*)(ws + o);                           // 2 planes packed
    float*  Sg  = ws + o;       o += (size_t)C_DIM*CAP;        // aliased: apply staging
    ushort* XcL = XcH + (size_t)C_DIM*CAP;
    ushort* XsH = (ushort*)(ws + o); o += (size_t)C_DIM*CAP;   // reused as XcT planes
    float* Af  = ws + o; o += (size_t)NMAT*MSZ;                // fp32 A; NS slot 4
    float* NS0 = ws + o; o += (size_t)4*NMAT*MSZ;              // NS slots 0..3 / syrk partials
    float* cmean = ws + o; o += 8*C_DIM;
    float* ssum  = ws + o; o += 8*C_DIM;
    float* smean = ws + o; o += 8*C_DIM;
    float* vvec  = ws + o; o += 8*C_DIM;
    float* tvals = ws + o; o += 16;
    float* t2vals= ws + o; o += 16;
    float* total = ws + o; o += 8;
    int* ip = (int*)(ws + o);
    int* permC    = ip; ip += CAP;
    int* permCinv = ip; ip += CAP;
    int* permS    = ip; ip += CAP;
    int* cntC  = ip; ip += 8;
    int* cntS  = ip; ip += 8;
    int* offC  = ip; ip += 9;
    int* offS  = ip; ip += 9;
    int* chC   = ip; ip += NCHUNK*8;
    int* chS   = ip; ip += NCHUNK*8;
    int* baseC = ip; ip += NCHUNK*8;
    int* baseS = ip; ip += NCHUNK*8;
    size_t need_bytes = (size_t)((char*)ip - (char*)d_ws);
    if (ws_size < need_bytes){
        hipMemcpyAsync(d_out, (const void*)cf, (size_t)out_size*sizeof(float),
                       hipMemcpyDeviceToDevice, stream);
        return;
    }
    float* Pf = NS0;                                   // SYRK partials (4 slices)
    // NS rotation slots (each NMAT*MSZ floats-worth):
    ushort* s0 = (ushort*)(NS0 + 0*(size_t)NMAT*MSZ);
    ushort* s1 = (ushort*)(NS0 + 1*(size_t)NMAT*MSZ);
    ushort* s2 = (ushort*)(NS0 + 2*(size_t)NMAT*MSZ);
    ushort* s3 = (ushort*)(NS0 + 3*(size_t)NMAT*MSZ);
    ushort* s4 = (ushort*)Af;

    k_chunk_hist<<<NCHUNK,256,0,stream>>>(cl, chC);
    k_chunk_hist<<<NCHUNK,256,0,stream>>>(sl, chS);
    k_scan<<<1,64,0,stream>>>(chC, cntC, offC, baseC);
    k_scan<<<1,64,0,stream>>>(chS, cntS, offS, baseS);
    k_place<<<NCHUNK,64,0,stream>>>(cl, baseC, permC, permCinv);
    k_place<<<NCHUNK,64,0,stream>>>(sl, baseS, permS, nullptr);

    dim3 gg(CAP/256, C_DIM);
    k_gather<<<gg,256,0,stream>>>(cf, permC, offC, cntC, XcH, XcL);
    k_gather<<<gg,256,0,stream>>>(sf, permS, offS, cntS, XsH, XsH + (size_t)C_DIM*CAP);

    k_segsum<true><<<dim3(8,16),256,0,stream>>>(XcH, XcL, offC, cntC, cmean);
    k_segsum<false><<<dim3(8,16),256,0,stream>>>(XsH, XsH + (size_t)C_DIM*CAP, offS, cntS, ssum);
    k_style_mean<<<1,256,0,stream>>>(scores, cntS, ssum, total, smean);

    // raw S2 for all 16 (cluster, src) pairs, triangular tiles, split-K=4
    k_syrk_mfma<<<NMAT*NSLICE*10,256,0,stream>>>(XcH, XsH, offC, offS, Pf);

    // transpose Xc planes into Xs region (Xs fully consumed above)
    k_transpose<<<dim3(CAP/64, C_DIM/64, 2),256,0,stream>>>(XcH, XsH);
    ushort* XT = XsH;

    k_reduceP<<<(NMAT*MSZ)/1024,256,0,stream>>>(Pf);
    k_assemble<<<dim3(MSZ/256,16),256,0,stream>>>(Pf, scores, total, cmean, smean, cntC, Af);

    k_norm1<0><<<NMAT,256,0,stream>>>(Af, tvals, nullptr);

    ushort* bY = s0;  ushort* bZ = s1;  ushort* bP = s2;
    ushort* fy = s3;  ushort* fz = s4;
    k_split_init<<<dim3(MSZ/256,NMAT),256,0,stream>>>(Af, tvals, bY, bZ);

    // tighten bound: Bsq = Y^2 (fp32 into s3, free), t2 = ||Bsq||_1, Y *= rsqrt(t2)
    k_mm_ns<2><<<NMAT*16,256,0,stream>>>(bY, bY, nullptr, (float*)s3, NMAT);
    k_norm1<1><<<NMAT,256,0,stream>>>((float*)s3, tvals, t2vals);
    k_rescale<<<dim3(MSZ/256,NMAT),256,0,stream>>>(bY, t2vals);

    for (int it=0; it<NIT; ++it){
        k_mm_ns<1><<<NMAT*16,256,0,stream>>>(bZ, bY, bP, nullptr, NMAT); // P = q(Z*Y)
        k_mm_ns2<<<NMAT*32,256,0,stream>>>(bY, bP, bZ, fy, fz);          // fy=Y*P, fz=P*Z
        ushort* t1;
        t1 = bY; bY = fy; fy = t1;
        t1 = bZ; bZ = fz; fz = t1;
    }
    // T[k] = Y_style[8+k] * Z_content[k], fp32 into free slot fy
    float* Tf = (float*)fy;
    k_mm_ns<2><<<8*16,256,0,stream>>>(bY + (size_t)8*2*MSZ, bZ, nullptr, Tf, 8);

    ushort* Msp = fz;  // other free slot
    k_buildM<<<dim3(MSZ/256,8),256,0,stream>>>(Tf, tvals, Msp);
    k_buildV<<<dim3(8,2),256,0,stream>>>(Tf, tvals, cmean, smean, vvec);

    k_apply_mfma<<<(CAP/128)*4,256,0,stream>>>(Msp, XT, vvec, offC, Sg);
    k_scatter<<<(C_DIM*WH)/256,256,0,stream>>>(Sg, permCinv, out);
}